// Round 5
// baseline (2253.272 us; speedup 1.0000x reference)
//
#include <hip/hip_runtime.h>
#include <hip/hip_cooperative_groups.h>
#include <math.h>

namespace cg = cooperative_groups;

#define BLOCK 256
#define EGRID 2048                 // edge-parallel / bulk kernels
#define SG    512                  // scan/sort kernels (fixed structure)
#define LGRID 400                  // cooperative loop grid (400*256 >= n)
#define NTHE (EGRID*BLOCK)
#define NWVE (NTHE/64)
#define NTHL (LGRID*BLOCK)
#define INF_ 0x7fffffff
#define TB   4096                  // bitset-tail threshold
#define SORTN 4096

struct KParams {
  const float* x;
  const int*   ei;
  const float* w;
  const float* bb;
  float* out;
  int n, e, d, out_size;
  int* ws;
  long long ws_ints;
};

struct Lay {
  float* score; int *ks1,*cursor;
  int *keyA,*idxA,*keyB,*idxB,*lrank;
  int *rank,*mr,*t1,*mis,*mm,*misPre,*r2c,*clus,*colPtr,*rowPtr;
  unsigned *bh,*dtot,*dbase,*btot,*bbase;
  int *cnts,*colSrc,*rowDst,*pairCnt;
  long long unionBase;
};

__device__ __host__ inline Lay mklay(int* ws, int n, int e) {
  Lay L;
  L.score=(float*)ws;
  L.ks1   = ws + (size_t)1*n;
  L.cursor= ws + (size_t)2*n;          // CSR cursor -> nodeIdx (tail)
  L.keyA  = ws + (size_t)3*n;          // sort key -> active list A
  L.idxA  = ws + (size_t)4*n;          // sort payload -> sorted tail list S
  L.keyB  = ws + (size_t)5*n;          // sort key -> active list B
  L.idxB  = ws + (size_t)6*n;          // sort payload -> sel list parity 0
  L.lrank = ws + (size_t)7*n;          // sort tmp -> sel list parity 1
  L.rank  = ws + (size_t)8*n;
  L.mr    = ws + (size_t)9*n;          // dense tmin temp; final khop result
  L.t1    = ws + (size_t)10*n;         // dense tor temp; fin temp
  L.mis   = ws + (size_t)11*n;
  L.mm    = ws + (size_t)12*n;         // a[] = active?rank:INF; fin temp
  L.misPre= ws + (size_t)13*n;         // sel[] flags; post misPre
  L.r2c   = ws + (size_t)14*n;
  L.clus  = ws + (size_t)15*n;
  L.colPtr= ws + (size_t)16*n;         // n+1
  L.rowPtr= ws + (size_t)17*n + 64;    // unused (layout keep)
  int* sm = ws + (size_t)18*n + 128;
  L.bh    = (unsigned*)sm;             // 256*SG
  L.dtot  = L.bh + 256*SG;             // 256 -> tail aliveW
  L.dbase = L.dtot + 256;              // 256 -> tail selW parity banks
  L.btot  = L.dbase + 256;             // SG
  L.bbase = L.btot + SG;               // SG
  L.cnts  = (int*)(L.bbase + SG);      // 16
  L.unionBase = 18ll*n + 128 + 256ll*SG + 512 + 2ll*SG + 16;
  L.colSrc  = ws + L.unionBase;        // e ints (in-CSR)
  L.rowDst  = L.colSrc + e;            // e ints -> tail bitset rows (bs)
  L.pairCnt = ws + L.unionBase;        // M*M ints (aliased, post-loop)
  return L;
}

// ---- unrolled gather reducers ----
__device__ inline int gmin_(const int* __restrict__ s, const int* __restrict__ val,
                            int p, int pe, int m) {
  for (; p+3 < pe; p += 4) {
    int a0=s[p],a1=s[p+1],a2=s[p+2],a3=s[p+3];
    int t0=val[a0],t1=val[a1],t2=val[a2],t3=val[a3];
    t0=min(t0,t1); t2=min(t2,t3); t0=min(t0,t2); if (t0<m) m=t0;
  }
  for (; p<pe; ++p){ int t=val[s[p]]; if (t<m) m=t; }
  return m;
}
__device__ inline int gor_(const int* __restrict__ s, const int* __restrict__ val,
                           int p, int pe, int m) {
  for (; p+3 < pe; p += 4) m |= val[s[p]] | val[s[p+1]] | val[s[p+2]] | val[s[p+3]];
  for (; p<pe; ++p) m |= val[s[p]];
  return m;
}
__device__ inline int gsum_(const int* __restrict__ s, const int* __restrict__ val,
                            int p, int pe, int m) {
  for (; p+3 < pe; p += 4) m += val[s[p]] + val[s[p+1]] + val[s[p+2]] + val[s[p+3]];
  for (; p<pe; ++p) m += val[s[p]];
  return m;
}

// ---------------- phase kernels ----------------
__global__ __launch_bounds__(BLOCK) void k_score(KParams P) {
  Lay L = mklay(P.ws, P.n, P.e);
  int gid = blockIdx.x*BLOCK + threadIdx.x;
  int lane = gid & 63, gwv = gid >> 6;
  int d4 = P.d >> 2;
  double bconst = (double)P.bb[0];
  const float4* w4 = (const float4*)P.w;
  for (int v = gwv; v < P.n; v += NWVE) {
    const float4* xr = (const float4*)(P.x + (size_t)v*P.d);
    double s = 0.0;
    for (int q = lane; q < d4; q += 64) {
      float4 xv = xr[q], wv = w4[q];
      s += (double)xv.x*wv.x + (double)xv.y*wv.y + (double)xv.z*wv.z + (double)xv.w*wv.w;
    }
    for (int off = 32; off > 0; off >>= 1) s += __shfl_down(s, off);
    if (lane == 0) L.score[v] = (float)(1.0/(1.0+exp(-(s+bconst))));
  }
  for (int v = gid; v < P.n; v += NTHE) L.ks1[v] = 0;
}

__global__ __launch_bounds__(BLOCK) void k_degree(KParams P) {
  Lay L = mklay(P.ws, P.n, P.e);
  const int* col = P.ei + P.e;
  int gid = blockIdx.x*BLOCK + threadIdx.x;
  for (int j = gid; j < P.e; j += NTHE) atomicAdd(&L.ks1[col[j]], 1);
}

__global__ __launch_bounds__(BLOCK) void k_scan1(KParams P) {
  Lay L = mklay(P.ws, P.n, P.e);
  __shared__ int lds[256];
  int tid = threadIdx.x, bid = blockIdx.x;
  int chunk = (P.n + SG - 1)/SG;
  int ig = bid*chunk + tid;
  bool valid = (tid < chunk) && (ig < P.n);
  int v2 = valid ? L.ks1[ig] : 0;
  lds[tid] = v2; __syncthreads();
  for (int off = 1; off < 256; off <<= 1) {
    int t = (tid >= off) ? lds[tid-off] : 0; __syncthreads();
    lds[tid] += t; __syncthreads();
  }
  if (valid) L.colPtr[ig] = lds[tid] - v2;
  if (tid == 0) L.btot[bid] = (unsigned)lds[255];
}

__global__ void k_scanB(KParams P, int cnt, int slot) {  // <<<1,64>>>
  Lay L = mklay(P.ws, P.n, P.e);
  int lane = threadIdx.x;
  unsigned running = 0;
  for (int r = 0; r*64 < cnt; ++r) {
    int idx = r*64 + lane;
    unsigned v = (idx < cnt) ? L.btot[idx] : 0u;
    unsigned incl = v;
    for (int off = 1; off < 64; off <<= 1) { unsigned t = __shfl_up(incl, off); if (lane >= off) incl += t; }
    if (idx < cnt) L.bbase[idx] = incl - v + running;
    running += __shfl(incl, 63);
  }
  if (lane == 0 && slot >= 0) L.cnts[slot] = (int)running;
}

__global__ __launch_bounds__(BLOCK) void k_scan3(KParams P) {
  Lay L = mklay(P.ws, P.n, P.e);
  int tid = threadIdx.x, bid = blockIdx.x;
  int chunk = (P.n + SG - 1)/SG;
  int ig = bid*chunk + tid;
  if (tid < chunk && ig < P.n) {
    int cp = L.colPtr[ig] + (int)L.bbase[bid];
    L.colPtr[ig] = cp; L.cursor[ig] = cp; L.ks1[ig] += 1;
  }
  if (bid == 0 && tid == 0) L.colPtr[P.n] = P.e;
}

__global__ __launch_bounds__(BLOCK) void k_csr(KParams P) {
  Lay L = mklay(P.ws, P.n, P.e);
  const int* row = P.ei; const int* col = P.ei + P.e;
  int gid = blockIdx.x*BLOCK + threadIdx.x;
  for (int j = gid; j < P.e; j += NTHE) {
    int pos = atomicAdd(&L.cursor[col[j]], 1);
    L.colSrc[pos] = row[j];
  }
}

__global__ __launch_bounds__(BLOCK) void k_keygen(KParams P) {
  Lay L = mklay(P.ws, P.n, P.e);
  int v = blockIdx.x*BLOCK + threadIdx.x;
  if (v >= P.n) return;
  int s = gsum_(L.colSrc, L.ks1, L.colPtr[v], L.colPtr[v+1], L.ks1[v]);
  float upd = L.score[v] / (float)s;
  unsigned u = __float_as_uint(upd);
  u = (u & 0x80000000u) ? (~u) : (u | 0x80000000u);
  ((unsigned*)L.keyA)[v] = ~u;
  ((unsigned*)L.idxA)[v] = (unsigned)v;
}

__global__ __launch_bounds__(BLOCK) void k_sort_local(KParams P, int pass) {
  Lay L = mklay(P.ws, P.n, P.e);
  __shared__ int ldsH[1024];
  int tid = threadIdx.x, bid = blockIdx.x, lane = tid & 63, wib = tid >> 6;
  unsigned* sk = (pass & 1) ? (unsigned*)L.keyB : (unsigned*)L.keyA;
  int shift = pass*8;
  for (int i = tid; i < 1024; i += BLOCK) ldsH[i] = 0;
  __syncthreads();
  int chunk = (P.n + SG - 1)/SG;
  int ig = bid*chunk + tid;
  bool valid = (tid < chunk) && (ig < P.n);
  int dig = 0;
  if (valid) dig = (int)((sk[ig] >> shift) & 255u);
  unsigned long long mmask = __ballot(valid);
  for (int b = 0; b < 8; ++b) {
    unsigned long long bm = __ballot((dig >> b) & 1);
    mmask &= ((dig >> b) & 1) ? bm : ~bm;
  }
  int lp = 0;
  if (valid) {
    lp = __popcll(mmask & ((1ull << lane) - 1ull));
    if (lp == 0) ldsH[wib*256 + dig] = __popcll(mmask);
  }
  __syncthreads();
  if (tid < 256) {
    int c0=ldsH[tid], c1=ldsH[256+tid], c2=ldsH[512+tid], c3=ldsH[768+tid];
    ldsH[tid]=0; ldsH[256+tid]=c0; ldsH[512+tid]=c0+c1; ldsH[768+tid]=c0+c1+c2;
    L.bh[(size_t)tid*SG + bid] = (unsigned)(c0+c1+c2+c3);
  }
  __syncthreads();
  if (valid) ((unsigned*)L.lrank)[ig] = (unsigned)(ldsH[wib*256 + dig] + lp);
}

__global__ __launch_bounds__(BLOCK) void k_sort_scan1(KParams P) {
  Lay L = mklay(P.ws, P.n, P.e);
  int g = blockIdx.x*BLOCK + threadIdx.x;
  int dg = g >> 6, lane = g & 63;
  if (dg >= 256) return;
  unsigned running = 0;
  for (int r = 0; r < SG/64; ++r) {
    unsigned v = L.bh[(size_t)dg*SG + r*64 + lane];
    unsigned incl = v;
    for (int off = 1; off < 64; off <<= 1) { unsigned t = __shfl_up(incl, off); if (lane >= off) incl += t; }
    L.bh[(size_t)dg*SG + r*64 + lane] = incl - v + running;
    running += __shfl(incl, 63);
  }
  if (lane == 0) L.dtot[dg] = running;
}

__global__ void k_scanD(KParams P) {   // <<<1,64>>>
  Lay L = mklay(P.ws, P.n, P.e);
  int lane = threadIdx.x;
  unsigned running = 0;
  for (int r = 0; r < 4; ++r) {
    unsigned v = L.dtot[r*64 + lane];
    unsigned incl = v;
    for (int off = 1; off < 64; off <<= 1) { unsigned t = __shfl_up(incl, off); if (lane >= off) incl += t; }
    L.dbase[r*64 + lane] = incl - v + running;
    running += __shfl(incl, 63);
  }
}

__global__ __launch_bounds__(BLOCK) void k_sort_scatter(KParams P, int pass) {
  Lay L = mklay(P.ws, P.n, P.e);
  unsigned *sk,*si,*dk,*di;
  if (pass & 1) { sk=(unsigned*)L.keyB; si=(unsigned*)L.idxB; dk=(unsigned*)L.keyA; di=(unsigned*)L.idxA; }
  else          { sk=(unsigned*)L.keyA; si=(unsigned*)L.idxA; dk=(unsigned*)L.keyB; di=(unsigned*)L.idxB; }
  int tid = threadIdx.x, bid = blockIdx.x;
  int chunk = (P.n + SG - 1)/SG;
  int ig = bid*chunk + tid;
  if (tid < chunk && ig < P.n) {
    unsigned key = sk[ig];
    int dig = (int)((key >> (pass*8)) & 255u);
    unsigned pos = L.dbase[dig] + L.bh[(size_t)dig*SG + bid] + ((unsigned*)L.lrank)[ig];
    dk[pos] = key; di[pos] = si[ig];
  }
}

__global__ __launch_bounds__(BLOCK) void k_rankinit(KParams P) {
  Lay L = mklay(P.ws, P.n, P.e);
  int i = blockIdx.x*BLOCK + threadIdx.x;
  if (blockIdx.x == 0 && threadIdx.x < 12) L.cnts[4 + threadIdx.x] = 0;
  if (i >= P.n) return;
  int v = (int)((unsigned*)L.idxA)[i];
  L.rank[v] = i;
  L.mm[v] = i;        // a[] = rank (all active)
  L.mis[v] = 0;
  L.misPre[v] = 0;    // sel[] = 0
}

// ---- cooperative loop: dense all-gather iterations + bitset tail ----
__global__ __launch_bounds__(BLOCK, 2) void k_loop(KParams P) {
  cg::grid_group grid = cg::this_grid();
  Lay L = mklay(P.ws, P.n, P.e);
  __shared__ int sK[SORTN];
  __shared__ int sV[SORTN];
  const int tid = threadIdx.x, bid = blockIdx.x;
  const int gid = bid*BLOCK + tid;
  const int lane = tid & 63;
  const int n = P.n;
  const int* __restrict__ cp = L.colPtr;
  const int* __restrict__ cs = L.colSrc;
  int* a    = L.mm;
  int* sel  = L.misPre;
  int* tmin = L.mr;
  int* tor  = L.t1;
  int* cn   = L.cnts;
  int* actBuf[2] = { L.keyA, L.keyB };
  int* selBuf[2] = { L.idxB, L.lrank };

  int q = 0, A = n, iter = 0;
  bool first = true;
  while ((first || A > TB) && A > 0 && iter < 100000) {
    const int nq = 1 - q;
    int* act = actBuf[q];
    int* selCur = selBuf[q];
    int* selPrev = selBuf[nq];
    const int prevSelCnt = first ? 0 : __hip_atomic_load(&cn[6+nq], __ATOMIC_RELAXED, __HIP_MEMORY_SCOPE_AGENT);
    // P1a: clear prev-round sel flags; dense 1-hop min of a
    for (int i = gid; i < prevSelCnt; i += NTHL) sel[selPrev[i]] = 0;
    if (gid == 0) cn[4+nq] = 0;
    for (int w = gid; w < n; w += NTHL)
      tmin[w] = gmin_(cs, a, cp[w], cp[w+1], a[w]);
    grid.sync();
    // P1b: 2-hop min at active; select
    for (int i = gid; i < A; i += NTHL) {
      int v = first ? i : act[i];
      int m2 = gmin_(cs, tmin, cp[v], cp[v+1], tmin[v]);
      if (L.rank[v] == m2) {
        L.mis[v] = 1; sel[v] = 1;
        int k = atomicAdd(&cn[6+q], 1); selCur[k] = v;
      }
    }
    grid.sync();
    // P2a: dense 1-hop or of sel
    for (int w = gid; w < n; w += NTHL)
      tor[w] = gor_(cs, sel, cp[w], cp[w+1], sel[w]);
    grid.sync();
    // P2b: 2-hop or at active; rebuild active list (wave-aggregated)
    if (gid == 0) cn[6+nq] = 0;
    int* nact = actBuf[nq];
    for (int ib = gid - lane; ib < A; ib += NTHL) {
      int i = ib + lane;
      bool in = (i < A);
      int v = 0; bool aliveF = false;
      if (in) {
        v = first ? i : act[i];
        int dead = gor_(cs, tor, cp[v], cp[v+1], tor[v]);
        if (dead) a[v] = INF_; else aliveF = true;
      }
      unsigned long long mk = __ballot(aliveF);
      int cntw = __popcll(mk);
      if (cntw) {
        int fl = __ffsll((unsigned long long)mk) - 1;
        int base = 0;
        if (lane == fl) base = atomicAdd(&cn[4+nq], cntw);
        base = __shfl(base, fl);
        if (aliveF) nact[base + __popcll(mk & ((1ull<<lane)-1ull))] = v;
      }
    }
    grid.sync();
    A = __hip_atomic_load(&cn[4+nq], __ATOMIC_RELAXED, __HIP_MEMORY_SCOPE_AGENT);
    q = nq; first = false; ++iter;
  }
  // ---------------- bitset tail (A <= TB, exact round semantics) ----------------
  if (A > 0) {
    int* act = actBuf[q];
    int* S = L.idxA;
    int* nodeIdx = L.cursor;
    unsigned* bs = (unsigned*)L.rowDst;        // A rows x 128 words
    unsigned* aliveW = L.dtot;                 // 128 words
    unsigned* selW   = L.dbase;                // 2 x 128 words
    const int AW = 128;
    // T1: nodeIdx = -1; zero rows; init alive/sel; block0 bitonic-sorts act by rank
    for (int v = gid; v < n; v += NTHL) nodeIdx[v] = -1;
    for (long long t = gid; t < (long long)A*AW; t += NTHL) bs[t] = 0;
    if (gid < 128) {
      int base = gid*32;
      unsigned am = 0;
      if (base < A) { int c = A - base; am = (c >= 32) ? 0xffffffffu : ((1u<<c)-1u); }
      aliveW[gid] = am;
      selW[gid] = 0; selW[128+gid] = 0;
    }
    if (bid == 0) {
      for (int t = tid; t < SORTN; t += BLOCK) {
        if (t < A) { int v = act[t]; sK[t] = L.rank[v]; sV[t] = v; }
        else { sK[t] = INF_; sV[t] = -1; }
      }
      for (int k = 2; k <= SORTN; k <<= 1)
        for (int j = k >> 1; j > 0; j >>= 1) {
          __syncthreads();
          for (int t = tid; t < SORTN; t += BLOCK) {
            int ixj = t ^ j;
            if (ixj > t) {
              bool up = ((t & k) == 0);
              int kt = sK[t], kx = sK[ixj];
              if ((kt > kx) == up) {
                sK[t] = kx; sK[ixj] = kt;
                int vt = sV[t]; sV[t] = sV[ixj]; sV[ixj] = vt;
              }
            }
          }
        }
      __syncthreads();
      for (int t = tid; t < A; t += BLOCK) S[t] = sV[t];
    }
    grid.sync();
    // T2: index map
    for (int i = gid; i < A; i += NTHL) nodeIdx[S[i]] = i;
    grid.sync();
    // T3: build in2closed source bitsets (single-writer rows, no atomics)
    for (int i = gid; i < A; i += NTHL) {
      int v = S[i];
      unsigned* row = bs + (size_t)i*AW;
      row[i >> 5] |= (1u << (i & 31));         // self
      int p1 = cp[v+1];
      for (int p = cp[v]; p < p1; ++p) {
        int u = cs[p];
        int j = nodeIdx[u];
        if (j >= 0) row[j >> 5] |= (1u << (j & 31));
        int p3 = cp[u+1];
        for (int p2 = cp[u]; p2 < p3; ++p2) {
          int w2 = cs[p2];
          int j2 = nodeIdx[w2];
          if (j2 >= 0) row[j2 >> 5] |= (1u << (j2 & 31));
        }
      }
    }
    grid.sync();
    // T4: rounds on bitsets
    int rounds = 0;
    for (;;) {
      const int p = rounds & 1;
      unsigned* sw = selW + p*128;
      // ph1: select alive i with no smaller-ranked alive in-2 source
      if (gid == 0) cn[12+p] = 0;
      for (int i = gid; i < A; i += NTHL) {
        if ((aliveW[i>>5] >> (i&31)) & 1u) {
          const unsigned* row = bs + (size_t)i*AW;
          int wlim = i >> 5;
          unsigned any = 0;
          for (int w2 = 0; w2 < wlim; ++w2) { any = row[w2] & aliveW[w2]; if (any) break; }
          if (!any) any = row[wlim] & aliveW[wlim] & ((i&31) ? ((1u<<(i&31))-1u) : 0u);
          if (!any) atomicOr(&sw[i>>5], 1u << (i&31));
        }
      }
      grid.sync();
      // ph2: mark mis, kill covered, count survivors
      for (int ib = gid - lane; ib < A; ib += NTHL) {
        int i = ib + lane;
        bool aliveF = false;
        if (i < A && ((aliveW[i>>5] >> (i&31)) & 1u)) {
          const unsigned* row = bs + (size_t)i*AW;
          if ((sw[i>>5] >> (i&31)) & 1u) L.mis[S[i]] = 1;
          unsigned dead = 0;
          for (int w2 = 0; w2 < AW; ++w2) { dead = row[w2] & sw[w2]; if (dead) break; }
          if (dead) atomicAnd(&aliveW[i>>5], ~(1u << (i&31)));
          else aliveF = true;
        }
        unsigned long long mk = __ballot(aliveF);
        int cntw = __popcll(mk);
        if (cntw && lane == (__ffsll((unsigned long long)mk)-1)) atomicAdd(&cn[12+p], cntw);
      }
      if (gid < 128) selW[(1-p)*128 + gid] = 0;   // pre-zero next-round sel bank
      grid.sync();
      int ac = __hip_atomic_load(&cn[12+p], __ATOMIC_RELAXED, __HIP_MEMORY_SCOPE_AGENT);
      if (ac == 0 || rounds >= 100000) break;
      ++rounds;
    }
  }
}

// ---- final khop_min over (mis ? rank : n) ----
__global__ __launch_bounds__(BLOCK) void k_fin0(KParams P) {
  Lay L = mklay(P.ws, P.n, P.e);
  int v = blockIdx.x*BLOCK + threadIdx.x;
  if (v >= P.n) return;
  L.mm[v] = L.mis[v] ? L.rank[v] : P.n;
}
__global__ __launch_bounds__(BLOCK) void k_fin1(KParams P) {
  Lay L = mklay(P.ws, P.n, P.e);
  int v = blockIdx.x*BLOCK + threadIdx.x;
  if (v >= P.n) return;
  L.t1[v] = gmin_(L.colSrc, L.mm, L.colPtr[v], L.colPtr[v+1], L.mm[v]);
}
__global__ __launch_bounds__(BLOCK) void k_fin2(KParams P) {
  Lay L = mklay(P.ws, P.n, P.e);
  int v = blockIdx.x*BLOCK + threadIdx.x;
  if (v >= P.n) return;
  L.mr[v] = gmin_(L.colSrc, L.t1, L.colPtr[v], L.colPtr[v+1], L.t1[v]);
}

// ---- mis prefix scan -> misPre, num_mis, r2c ----
__global__ __launch_bounds__(BLOCK) void k_scanM1(KParams P) {
  Lay L = mklay(P.ws, P.n, P.e);
  __shared__ int lds[256];
  int tid = threadIdx.x, bid = blockIdx.x;
  int chunk = (P.n + SG - 1)/SG;
  int ig = bid*chunk + tid;
  bool valid = (tid < chunk) && (ig < P.n);
  int v2 = valid ? L.mis[ig] : 0;
  lds[tid] = v2; __syncthreads();
  for (int off = 1; off < 256; off <<= 1) {
    int t = (tid >= off) ? lds[tid-off] : 0; __syncthreads();
    lds[tid] += t; __syncthreads();
  }
  if (valid) L.misPre[ig] = lds[tid] - v2;
  if (tid == 0) L.btot[bid] = (unsigned)lds[255];
}
__global__ __launch_bounds__(BLOCK) void k_scanM3(KParams P) {
  Lay L = mklay(P.ws, P.n, P.e);
  int tid = threadIdx.x, bid = blockIdx.x;
  int chunk = (P.n + SG - 1)/SG;
  int ig = bid*chunk + tid;
  if (tid < chunk && ig < P.n) {
    int p = L.misPre[ig] + (int)L.bbase[bid];
    L.misPre[ig] = p;
    if (L.mis[ig]) L.r2c[L.rank[ig]] = p;
  }
}

__global__ __launch_bounds__(BLOCK) void k_clus(KParams P) {
  Lay L = mklay(P.ws, P.n, P.e);
  int gid = blockIdx.x*BLOCK + threadIdx.x;
  int M = L.cnts[2];
  long long M2 = (long long)M*M;
  for (int v = gid; v < P.n; v += NTHE) {
    int r3 = L.mr[v];
    L.clus[v] = (r3 >= 0 && r3 < P.n) ? L.r2c[r3] : 0;
  }
  bool pairOk = (M > 0) && (M2 < 0x7fffffffll) && (L.unionBase + M2 <= P.ws_ints);
  if (pairOk) {
    int m2i = (int)M2;
    for (int i = gid; i < m2i; i += NTHE) L.pairCnt[i] = 0;
  }
}

__global__ __launch_bounds__(BLOCK) void k_pair(KParams P) {
  Lay L = mklay(P.ws, P.n, P.e);
  int M = L.cnts[2];
  long long M2 = (long long)M*M;
  bool pairOk = (M > 0) && (M2 < 0x7fffffffll) && (L.unionBase + M2 <= P.ws_ints);
  if (!pairOk) return;
  const int* row = P.ei; const int* col = P.ei + P.e;
  int gid = blockIdx.x*BLOCK + threadIdx.x;
  for (int j = gid; j < P.e; j += NTHE) {
    int a = L.clus[row[j]], b2 = L.clus[col[j]];
    atomicAdd(&L.pairCnt[a*M + b2], 1);
  }
}

__global__ __launch_bounds__(BLOCK) void k_keep1(KParams P) {
  Lay L = mklay(P.ws, P.n, P.e);
  __shared__ int lds[256];
  int tid = threadIdx.x, bid = blockIdx.x;
  int M = L.cnts[2];
  long long M2 = (long long)M*M;
  bool pairOk = (M > 0) && (M2 < 0x7fffffffll) && (L.unionBase + M2 <= P.ws_ints);
  int m2i = pairOk ? (int)M2 : 0;
  int chunkP = pairOk ? (m2i + SG - 1)/SG : 0;
  int pstart = bid*chunkP; if (pstart > m2i) pstart = m2i;
  int pend = pstart + chunkP; if (pend > m2i) pend = m2i;
  int localKeep = 0;
  for (int i = pstart + tid; i < pend; i += BLOCK) {
    int c = L.pairCnt[i];
    if (c > 0 && (i / M) != (i % M)) ++localKeep;
  }
  lds[tid] = localKeep; __syncthreads();
  for (int off = 128; off > 0; off >>= 1) { if (tid < off) lds[tid] += lds[tid+off]; __syncthreads(); }
  if (tid == 0) L.btot[bid] = (unsigned)lds[0];
}

__global__ __launch_bounds__(BLOCK) void k_edges(KParams P) {
  Lay L = mklay(P.ws, P.n, P.e);
  __shared__ int lds[256];
  int tid = threadIdx.x, bid = blockIdx.x;
  int M = L.cnts[2], EK = L.cnts[3];
  long long M2 = (long long)M*M;
  bool pairOk = (M > 0) && (M2 < 0x7fffffffll) && (L.unionBase + M2 <= P.ws_ints);
  if (!pairOk) return;
  int m2i = (int)M2;
  int chunkP = (m2i + SG - 1)/SG;
  int pstart = bid*chunkP; if (pstart > m2i) pstart = m2i;
  int pend = pstart + chunkP; if (pend > m2i) pend = m2i;
  size_t eBase = (size_t)M * (size_t)P.d;
  bool outOk = (eBase + 3ull*(size_t)EK <= (size_t)P.out_size);
  int running2 = (int)L.bbase[bid];
  for (int t0 = pstart; t0 < pend; t0 += BLOCK) {
    int i = t0 + tid;
    int c = 0, kept = 0, a = 0, b2 = 0;
    if (i < pend) {
      c = L.pairCnt[i];
      a = i / M; b2 = i % M;
      kept = (c > 0 && a != b2) ? 1 : 0;
    }
    lds[tid] = kept; __syncthreads();
    for (int off = 1; off < 256; off <<= 1) {
      int t = (tid >= off) ? lds[tid-off] : 0; __syncthreads();
      lds[tid] += t; __syncthreads();
    }
    int incl = lds[tid], tot = lds[255];
    if (kept && outOk) {
      int j2 = running2 + incl - 1;
      P.out[eBase + (size_t)j2] = (float)a;
      P.out[eBase + (size_t)EK + (size_t)j2] = (float)b2;
      P.out[eBase + 2ull*(size_t)EK + (size_t)j2] = (float)c;
    }
    running2 += tot;
    __syncthreads();
  }
}

__global__ __launch_bounds__(BLOCK) void k_xpool(KParams P) {
  Lay L = mklay(P.ws, P.n, P.e);
  int gid = blockIdx.x*BLOCK + threadIdx.x;
  int lane = gid & 63, gwv = gid >> 6;
  int M = L.cnts[2];
  int d4 = P.d >> 2;
  size_t eBase = (size_t)M * (size_t)P.d;
  if (eBase > (size_t)P.out_size) return;
  for (int v = gwv; v < P.n; v += NWVE) {
    if (L.mis[v]) {
      int p = L.misPre[v];
      float sc = L.score[v];
      const float4* xr = (const float4*)(P.x + (size_t)v*P.d);
      float4* outr = (float4*)P.out + (size_t)p*d4;
      for (int q = lane; q < d4; q += 64) {
        float4 xv = xr[q];
        outr[q] = make_float4(xv.x*sc, xv.y*sc, xv.z*sc, xv.w*sc);
      }
    }
  }
}

extern "C" void kernel_launch(void* const* d_in, const int* in_sizes, int n_in,
                              void* d_out, int out_size, void* d_ws, size_t ws_size,
                              hipStream_t stream) {
  KParams P;
  P.x  = (const float*)d_in[0];
  P.ei = (const int*)d_in[1];
  P.w  = (const float*)d_in[2];
  P.bb = (const float*)d_in[3];
  P.out = (float*)d_out;
  P.d = in_sizes[2];            // 256
  P.n = in_sizes[0] / P.d;      // 100000
  P.e = in_sizes[1] / 2;        // 1600000
  P.out_size = out_size;
  P.ws = (int*)d_ws;
  P.ws_ints = (long long)(ws_size / 4);
  const int nblk = (P.n + BLOCK - 1) / BLOCK;

  k_score <<<EGRID, BLOCK, 0, stream>>>(P);
  k_degree<<<EGRID, BLOCK, 0, stream>>>(P);
  k_scan1 <<<SG,    BLOCK, 0, stream>>>(P);
  k_scanB <<<1, 64, 0, stream>>>(P, SG, -1);
  k_scan3 <<<SG,    BLOCK, 0, stream>>>(P);
  k_csr   <<<EGRID, BLOCK, 0, stream>>>(P);
  k_keygen<<<nblk,  BLOCK, 0, stream>>>(P);
  for (int pass = 0; pass < 4; ++pass) {
    k_sort_local  <<<SG, BLOCK, 0, stream>>>(P, pass);
    k_sort_scan1  <<<64, BLOCK, 0, stream>>>(P);
    k_scanD       <<<1, 64,    0, stream>>>(P);
    k_sort_scatter<<<SG, BLOCK, 0, stream>>>(P, pass);
  }
  k_rankinit<<<nblk, BLOCK, 0, stream>>>(P);
  void* args[] = { &P };
  hipLaunchCooperativeKernel((const void*)k_loop, dim3(LGRID), dim3(BLOCK), args, 0, stream);
  k_fin0<<<nblk, BLOCK, 0, stream>>>(P);
  k_fin1<<<nblk, BLOCK, 0, stream>>>(P);
  k_fin2<<<nblk, BLOCK, 0, stream>>>(P);
  k_scanM1<<<SG, BLOCK, 0, stream>>>(P);
  k_scanB <<<1, 64, 0, stream>>>(P, SG, 2);
  k_scanM3<<<SG, BLOCK, 0, stream>>>(P);
  k_clus <<<EGRID, BLOCK, 0, stream>>>(P);
  k_pair <<<EGRID, BLOCK, 0, stream>>>(P);
  k_keep1<<<SG,    BLOCK, 0, stream>>>(P);
  k_scanB<<<1, 64, 0, stream>>>(P, SG, 3);
  k_edges<<<SG,    BLOCK, 0, stream>>>(P);
  k_xpool<<<EGRID, BLOCK, 0, stream>>>(P);
}

// Round 6
// 1382.274 us; speedup vs baseline: 1.6301x; 1.6301x over previous
//
#include <hip/hip_runtime.h>
#include <hip/hip_cooperative_groups.h>
#include <math.h>

namespace cg = cooperative_groups;

#define BLOCK 256
#define EGRID 2048                 // edge-parallel / bulk kernels
#define SG    512                  // scan/sort kernels (fixed structure)
#define TGRID 64                   // cooperative tail grid (small => cheap grid.sync)
#define NTHE (EGRID*BLOCK)
#define NWVE (NTHE/64)
#define NTHT (TGRID*BLOCK)
#define INF_ 0x7fffffff
#define TB   4096                  // bitset-tail threshold
#define SORTN 4096
#define DENSE_ITERS 6

struct KParams {
  const float* x;
  const int*   ei;
  const float* w;
  const float* bb;
  float* out;
  int n, e, d, out_size;
  int* ws;
  long long ws_ints;
};

struct Lay {
  float* score; int *ks1,*cursor;
  int *keyA,*idxA,*keyB,*idxB,*lrank;
  int *rank,*mr,*t1,*mis,*mm,*misPre,*r2c,*clus,*colPtr,*rowPtr;
  unsigned *bh,*dtot,*dbase,*btot,*bbase;
  int *cnts,*colSrc,*rowDst,*pairCnt;
  long long unionBase;
};

__device__ __host__ inline Lay mklay(int* ws, int n, int e) {
  Lay L;
  L.score=(float*)ws;
  L.ks1   = ws + (size_t)1*n;
  L.cursor= ws + (size_t)2*n;          // CSR cursor -> nodeIdx (tail)
  L.keyA  = ws + (size_t)3*n;          // sort key -> active list parity 0
  L.idxA  = ws + (size_t)4*n;          // sort payload -> sorted tail list S
  L.keyB  = ws + (size_t)5*n;          // sort key -> active list parity 1
  L.idxB  = ws + (size_t)6*n;
  L.lrank = ws + (size_t)7*n;
  L.rank  = ws + (size_t)8*n;
  L.mr    = ws + (size_t)9*n;          // tmin temp; final khop result
  L.t1    = ws + (size_t)10*n;         // tor temp; fin temp
  L.mis   = ws + (size_t)11*n;
  L.mm    = ws + (size_t)12*n;         // a[] = active?rank:INF; fin temp
  L.misPre= ws + (size_t)13*n;         // post misPre
  L.r2c   = ws + (size_t)14*n;
  L.clus  = ws + (size_t)15*n;
  L.colPtr= ws + (size_t)16*n;         // n+1
  L.rowPtr= ws + (size_t)17*n + 64;    // unused (layout keep)
  int* sm = ws + (size_t)18*n + 128;
  L.bh    = (unsigned*)sm;             // 256*SG
  L.dtot  = L.bh + 256*SG;             // 256 -> tail aliveW
  L.dbase = L.dtot + 256;              // 256 -> tail selW parity banks
  L.btot  = L.dbase + 256;             // SG
  L.bbase = L.btot + SG;               // SG
  L.cnts  = (int*)(L.bbase + SG);      // 16
  L.unionBase = 18ll*n + 128 + 256ll*SG + 512 + 2ll*SG + 16;
  L.colSrc  = ws + L.unionBase;        // e ints (in-CSR)
  L.rowDst  = L.colSrc + e;            // e ints -> tail bitset rows (bs)
  L.pairCnt = ws + L.unionBase;        // M*M ints (aliased, post-loop)
  return L;
}

// ---- unrolled gather reducers ----
__device__ inline int gmin_(const int* __restrict__ s, const int* __restrict__ val,
                            int p, int pe, int m) {
  for (; p+3 < pe; p += 4) {
    int a0=s[p],a1=s[p+1],a2=s[p+2],a3=s[p+3];
    int t0=val[a0],t1=val[a1],t2=val[a2],t3=val[a3];
    t0=min(t0,t1); t2=min(t2,t3); t0=min(t0,t2); if (t0<m) m=t0;
  }
  for (; p<pe; ++p){ int t=val[s[p]]; if (t<m) m=t; }
  return m;
}
__device__ inline int gor_(const int* __restrict__ s, const int* __restrict__ val,
                           int p, int pe, int m) {
  for (; p+3 < pe; p += 4) m |= val[s[p]] | val[s[p+1]] | val[s[p+2]] | val[s[p+3]];
  for (; p<pe; ++p) m |= val[s[p]];
  return m;
}
__device__ inline int gsum_(const int* __restrict__ s, const int* __restrict__ val,
                            int p, int pe, int m) {
  for (; p+3 < pe; p += 4) m += val[s[p]] + val[s[p+1]] + val[s[p+2]] + val[s[p+3]];
  for (; p<pe; ++p) m += val[s[p]];
  return m;
}

// ---------------- phase kernels ----------------
__global__ __launch_bounds__(BLOCK) void k_score(KParams P) {
  Lay L = mklay(P.ws, P.n, P.e);
  int gid = blockIdx.x*BLOCK + threadIdx.x;
  int lane = gid & 63, gwv = gid >> 6;
  int d4 = P.d >> 2;
  double bconst = (double)P.bb[0];
  const float4* w4 = (const float4*)P.w;
  for (int v = gwv; v < P.n; v += NWVE) {
    const float4* xr = (const float4*)(P.x + (size_t)v*P.d);
    double s = 0.0;
    for (int q = lane; q < d4; q += 64) {
      float4 xv = xr[q], wv = w4[q];
      s += (double)xv.x*wv.x + (double)xv.y*wv.y + (double)xv.z*wv.z + (double)xv.w*wv.w;
    }
    for (int off = 32; off > 0; off >>= 1) s += __shfl_down(s, off);
    if (lane == 0) L.score[v] = (float)(1.0/(1.0+exp(-(s+bconst))));
  }
  for (int v = gid; v < P.n; v += NTHE) L.ks1[v] = 0;
}

__global__ __launch_bounds__(BLOCK) void k_degree(KParams P) {
  Lay L = mklay(P.ws, P.n, P.e);
  const int* col = P.ei + P.e;
  int gid = blockIdx.x*BLOCK + threadIdx.x;
  for (int j = gid; j < P.e; j += NTHE) atomicAdd(&L.ks1[col[j]], 1);
}

__global__ __launch_bounds__(BLOCK) void k_scan1(KParams P) {
  Lay L = mklay(P.ws, P.n, P.e);
  __shared__ int lds[256];
  int tid = threadIdx.x, bid = blockIdx.x;
  int chunk = (P.n + SG - 1)/SG;
  int ig = bid*chunk + tid;
  bool valid = (tid < chunk) && (ig < P.n);
  int v2 = valid ? L.ks1[ig] : 0;
  lds[tid] = v2; __syncthreads();
  for (int off = 1; off < 256; off <<= 1) {
    int t = (tid >= off) ? lds[tid-off] : 0; __syncthreads();
    lds[tid] += t; __syncthreads();
  }
  if (valid) L.colPtr[ig] = lds[tid] - v2;
  if (tid == 0) L.btot[bid] = (unsigned)lds[255];
}

__global__ void k_scanB(KParams P, int cnt, int slot) {  // <<<1,64>>>
  Lay L = mklay(P.ws, P.n, P.e);
  int lane = threadIdx.x;
  unsigned running = 0;
  for (int r = 0; r*64 < cnt; ++r) {
    int idx = r*64 + lane;
    unsigned v = (idx < cnt) ? L.btot[idx] : 0u;
    unsigned incl = v;
    for (int off = 1; off < 64; off <<= 1) { unsigned t = __shfl_up(incl, off); if (lane >= off) incl += t; }
    if (idx < cnt) L.bbase[idx] = incl - v + running;
    running += __shfl(incl, 63);
  }
  if (lane == 0 && slot >= 0) L.cnts[slot] = (int)running;
}

__global__ __launch_bounds__(BLOCK) void k_scan3(KParams P) {
  Lay L = mklay(P.ws, P.n, P.e);
  int tid = threadIdx.x, bid = blockIdx.x;
  int chunk = (P.n + SG - 1)/SG;
  int ig = bid*chunk + tid;
  if (tid < chunk && ig < P.n) {
    int cp = L.colPtr[ig] + (int)L.bbase[bid];
    L.colPtr[ig] = cp; L.cursor[ig] = cp; L.ks1[ig] += 1;
  }
  if (bid == 0 && tid == 0) L.colPtr[P.n] = P.e;
}

__global__ __launch_bounds__(BLOCK) void k_csr(KParams P) {
  Lay L = mklay(P.ws, P.n, P.e);
  const int* row = P.ei; const int* col = P.ei + P.e;
  int gid = blockIdx.x*BLOCK + threadIdx.x;
  for (int j = gid; j < P.e; j += NTHE) {
    int pos = atomicAdd(&L.cursor[col[j]], 1);
    L.colSrc[pos] = row[j];
  }
}

__global__ __launch_bounds__(BLOCK) void k_keygen(KParams P) {
  Lay L = mklay(P.ws, P.n, P.e);
  int v = blockIdx.x*BLOCK + threadIdx.x;
  if (v >= P.n) return;
  int s = gsum_(L.colSrc, L.ks1, L.colPtr[v], L.colPtr[v+1], L.ks1[v]);
  float upd = L.score[v] / (float)s;
  unsigned u = __float_as_uint(upd);
  u = (u & 0x80000000u) ? (~u) : (u | 0x80000000u);
  ((unsigned*)L.keyA)[v] = ~u;
  ((unsigned*)L.idxA)[v] = (unsigned)v;
}

__global__ __launch_bounds__(BLOCK) void k_sort_local(KParams P, int pass) {
  Lay L = mklay(P.ws, P.n, P.e);
  __shared__ int ldsH[1024];
  int tid = threadIdx.x, bid = blockIdx.x, lane = tid & 63, wib = tid >> 6;
  unsigned* sk = (pass & 1) ? (unsigned*)L.keyB : (unsigned*)L.keyA;
  int shift = pass*8;
  for (int i = tid; i < 1024; i += BLOCK) ldsH[i] = 0;
  __syncthreads();
  int chunk = (P.n + SG - 1)/SG;
  int ig = bid*chunk + tid;
  bool valid = (tid < chunk) && (ig < P.n);
  int dig = 0;
  if (valid) dig = (int)((sk[ig] >> shift) & 255u);
  unsigned long long mmask = __ballot(valid);
  for (int b = 0; b < 8; ++b) {
    unsigned long long bm = __ballot((dig >> b) & 1);
    mmask &= ((dig >> b) & 1) ? bm : ~bm;
  }
  int lp = 0;
  if (valid) {
    lp = __popcll(mmask & ((1ull << lane) - 1ull));
    if (lp == 0) ldsH[wib*256 + dig] = __popcll(mmask);
  }
  __syncthreads();
  if (tid < 256) {
    int c0=ldsH[tid], c1=ldsH[256+tid], c2=ldsH[512+tid], c3=ldsH[768+tid];
    ldsH[tid]=0; ldsH[256+tid]=c0; ldsH[512+tid]=c0+c1; ldsH[768+tid]=c0+c1+c2;
    L.bh[(size_t)tid*SG + bid] = (unsigned)(c0+c1+c2+c3);
  }
  __syncthreads();
  if (valid) ((unsigned*)L.lrank)[ig] = (unsigned)(ldsH[wib*256 + dig] + lp);
}

__global__ __launch_bounds__(BLOCK) void k_sort_scan1(KParams P) {
  Lay L = mklay(P.ws, P.n, P.e);
  int g = blockIdx.x*BLOCK + threadIdx.x;
  int dg = g >> 6, lane = g & 63;
  if (dg >= 256) return;
  unsigned running = 0;
  for (int r = 0; r < SG/64; ++r) {
    unsigned v = L.bh[(size_t)dg*SG + r*64 + lane];
    unsigned incl = v;
    for (int off = 1; off < 64; off <<= 1) { unsigned t = __shfl_up(incl, off); if (lane >= off) incl += t; }
    L.bh[(size_t)dg*SG + r*64 + lane] = incl - v + running;
    running += __shfl(incl, 63);
  }
  if (lane == 0) L.dtot[dg] = running;
}

__global__ void k_scanD(KParams P) {   // <<<1,64>>>
  Lay L = mklay(P.ws, P.n, P.e);
  int lane = threadIdx.x;
  unsigned running = 0;
  for (int r = 0; r < 4; ++r) {
    unsigned v = L.dtot[r*64 + lane];
    unsigned incl = v;
    for (int off = 1; off < 64; off <<= 1) { unsigned t = __shfl_up(incl, off); if (lane >= off) incl += t; }
    L.dbase[r*64 + lane] = incl - v + running;
    running += __shfl(incl, 63);
  }
}

__global__ __launch_bounds__(BLOCK) void k_sort_scatter(KParams P, int pass) {
  Lay L = mklay(P.ws, P.n, P.e);
  unsigned *sk,*si,*dk,*di;
  if (pass & 1) { sk=(unsigned*)L.keyB; si=(unsigned*)L.idxB; dk=(unsigned*)L.keyA; di=(unsigned*)L.idxA; }
  else          { sk=(unsigned*)L.keyA; si=(unsigned*)L.idxA; dk=(unsigned*)L.keyB; di=(unsigned*)L.idxB; }
  int tid = threadIdx.x, bid = blockIdx.x;
  int chunk = (P.n + SG - 1)/SG;
  int ig = bid*chunk + tid;
  if (tid < chunk && ig < P.n) {
    unsigned key = sk[ig];
    int dig = (int)((key >> (pass*8)) & 255u);
    unsigned pos = L.dbase[dig] + L.bh[(size_t)dig*SG + bid] + ((unsigned*)L.lrank)[ig];
    dk[pos] = key; di[pos] = si[ig];
  }
}

__global__ __launch_bounds__(BLOCK) void k_rankinit(KParams P) {
  Lay L = mklay(P.ws, P.n, P.e);
  int i = blockIdx.x*BLOCK + threadIdx.x;
  if (blockIdx.x == 0 && threadIdx.x == 0) {
    L.cnts[4] = P.n;   // A for parity 0 (implicit identity list at iter 0)
    L.cnts[5] = 0;
    L.cnts[7] = 0;     // current parity
    L.cnts[12] = 0; L.cnts[13] = 0;
  }
  if (i >= P.n) return;
  int v = (int)((unsigned*)L.idxA)[i];
  L.rank[v] = i;
  L.mm[v] = i;        // a[] = rank (all active)
  L.mis[v] = 0;
}

// ---- dense KMIS iterations (standalone, attribution-friendly) ----
// tmin = 1-hop min of a[]
__global__ __launch_bounds__(BLOCK) void k_dmin(KParams P) {
  Lay L = mklay(P.ws, P.n, P.e);
  int q = L.cnts[7];
  if (L.cnts[4+q] <= TB) return;
  int w = blockIdx.x*BLOCK + threadIdx.x;
  if (w >= P.n) return;
  L.mr[w] = gmin_(L.colSrc, L.mm, L.colPtr[w], L.colPtr[w+1], L.mm[w]);
}
// 2-hop min at active; select into mis
__global__ __launch_bounds__(BLOCK) void k_dsel(KParams P, int first) {
  Lay L = mklay(P.ws, P.n, P.e);
  int q = L.cnts[7];
  int A = L.cnts[4+q];
  if (A <= TB) return;
  int i = blockIdx.x*BLOCK + threadIdx.x;
  if (i >= A) return;
  int v = first ? i : (q ? L.keyB : L.keyA)[i];
  int m2 = gmin_(L.colSrc, L.mr, L.colPtr[v], L.colPtr[v+1], L.mr[v]);
  if (L.rank[v] == m2) L.mis[v] = 1;
}
// tor = 1-hop or of mis; zero next-parity count
__global__ __launch_bounds__(BLOCK) void k_dor(KParams P) {
  Lay L = mklay(P.ws, P.n, P.e);
  int q = L.cnts[7];
  if (L.cnts[4+q] <= TB) return;
  int w = blockIdx.x*BLOCK + threadIdx.x;
  if (blockIdx.x == 0 && threadIdx.x == 0) L.cnts[4+(1-q)] = 0;
  if (w >= P.n) return;
  L.t1[w] = gor_(L.colSrc, L.mis, L.colPtr[w], L.colPtr[w+1], L.mis[w]);
}
// 2-hop or at active; survivors -> next-parity list (wave-aggregated)
__global__ __launch_bounds__(BLOCK) void k_drb(KParams P, int first) {
  Lay L = mklay(P.ws, P.n, P.e);
  int q = L.cnts[7];
  int A = L.cnts[4+q];
  if (A <= TB) return;
  int i = blockIdx.x*BLOCK + threadIdx.x;
  int lane = threadIdx.x & 63;
  int* nact = (q ? L.keyA : L.keyB);
  bool aliveF = false; int v = 0;
  if (i < A) {
    v = first ? i : (q ? L.keyB : L.keyA)[i];
    int dead = gor_(L.colSrc, L.t1, L.colPtr[v], L.colPtr[v+1], L.t1[v]);
    if (dead) L.mm[v] = INF_; else aliveF = true;
  }
  unsigned long long mk = __ballot(aliveF);
  int cntw = __popcll(mk);
  if (cntw) {
    int fl = __ffsll((unsigned long long)mk) - 1;
    int base = 0;
    if (lane == fl) base = atomicAdd(&L.cnts[4+(1-q)], cntw);
    base = __shfl(base, fl);
    if (aliveF) nact[base + __popcll(mk & ((1ull<<lane)-1ull))] = v;
  }
}
// flip parity iff this iteration actually ran  <<<1,1>>>
__global__ void k_dflip(KParams P) {
  Lay L = mklay(P.ws, P.n, P.e);
  int q = L.cnts[7];
  if (L.cnts[4+q] > TB) L.cnts[7] = 1 - q;
}

// ---- cooperative bitset tail (A <= TB expected; safety dense loop included) ----
__global__ __launch_bounds__(BLOCK, 2) void k_tail(KParams P) {
  cg::grid_group grid = cg::this_grid();
  Lay L = mklay(P.ws, P.n, P.e);
  __shared__ int sK[SORTN];
  __shared__ int sV[SORTN];
  const int tid = threadIdx.x, bid = blockIdx.x;
  const int gid = bid*BLOCK + tid;
  const int lane = tid & 63;
  const int n = P.n;
  const int* __restrict__ cp = L.colPtr;
  const int* __restrict__ cs = L.colSrc;
  int* a    = L.mm;
  int* tmin = L.mr;
  int* tor  = L.t1;
  int* cn   = L.cnts;
  int q = cn[7];
  int A = cn[4+q];
  // safety dense loop (not expected to trigger after DENSE_ITERS)
  while (A > TB) {
    int* act  = q ? L.keyB : L.keyA;
    int* nact = q ? L.keyA : L.keyB;
    for (int w = gid; w < n; w += NTHT) tmin[w] = gmin_(cs, a, cp[w], cp[w+1], a[w]);
    grid.sync();
    for (int i = gid; i < A; i += NTHT) {
      int v = act[i];
      int m2 = gmin_(cs, tmin, cp[v], cp[v+1], tmin[v]);
      if (L.rank[v] == m2) L.mis[v] = 1;
    }
    if (gid == 0) cn[4+(1-q)] = 0;
    grid.sync();
    for (int w = gid; w < n; w += NTHT) tor[w] = gor_(cs, L.mis, cp[w], cp[w+1], L.mis[w]);
    grid.sync();
    for (int ib = gid - lane; ib < A; ib += NTHT) {
      int i = ib + lane;
      bool aliveF = false; int v = 0;
      if (i < A) {
        v = act[i];
        int dead = gor_(cs, tor, cp[v], cp[v+1], tor[v]);
        if (dead) a[v] = INF_; else aliveF = true;
      }
      unsigned long long mk = __ballot(aliveF);
      int cntw = __popcll(mk);
      if (cntw) {
        int fl = __ffsll((unsigned long long)mk) - 1;
        int base = 0;
        if (lane == fl) base = atomicAdd(&cn[4+(1-q)], cntw);
        base = __shfl(base, fl);
        if (aliveF) nact[base + __popcll(mk & ((1ull<<lane)-1ull))] = v;
      }
    }
    grid.sync();
    q = 1 - q;
    A = __hip_atomic_load(&cn[4+q], __ATOMIC_RELAXED, __HIP_MEMORY_SCOPE_AGENT);
  }
  // ---------------- bitset tail ----------------
  if (A > 0) {
    int* act = q ? L.keyB : L.keyA;
    int* S = L.idxA;
    int* nodeIdx = L.cursor;
    unsigned* bs = (unsigned*)L.rowDst;        // A rows x 128 words
    unsigned* aliveW = L.dtot;                 // 128 words
    unsigned* selW   = L.dbase;                // 2 x 128 words
    const int AW = 128;
    for (int v = gid; v < n; v += NTHT) nodeIdx[v] = -1;
    for (long long t = gid; t < (long long)A*AW; t += NTHT) bs[t] = 0;
    if (gid < 128) {
      int base = gid*32;
      unsigned am = 0;
      if (base < A) { int c = A - base; am = (c >= 32) ? 0xffffffffu : ((1u<<c)-1u); }
      aliveW[gid] = am;
      selW[gid] = 0; selW[128+gid] = 0;
    }
    if (bid == 0) {
      for (int t = tid; t < SORTN; t += BLOCK) {
        if (t < A) { int v = act[t]; sK[t] = L.rank[v]; sV[t] = v; }
        else { sK[t] = INF_; sV[t] = -1; }
      }
      for (int k = 2; k <= SORTN; k <<= 1)
        for (int j = k >> 1; j > 0; j >>= 1) {
          __syncthreads();
          for (int t = tid; t < SORTN; t += BLOCK) {
            int ixj = t ^ j;
            if (ixj > t) {
              bool up = ((t & k) == 0);
              int kt = sK[t], kx = sK[ixj];
              if ((kt > kx) == up) {
                sK[t] = kx; sK[ixj] = kt;
                int vt = sV[t]; sV[t] = sV[ixj]; sV[ixj] = vt;
              }
            }
          }
        }
      __syncthreads();
      for (int t = tid; t < A; t += BLOCK) S[t] = sV[t];
    }
    grid.sync();
    for (int i = gid; i < A; i += NTHT) nodeIdx[S[i]] = i;
    grid.sync();
    // build in2closed source bitsets (single-writer rows)
    for (int i = gid; i < A; i += NTHT) {
      int v = S[i];
      unsigned* row = bs + (size_t)i*AW;
      row[i >> 5] |= (1u << (i & 31));
      int p1 = cp[v+1];
      for (int p = cp[v]; p < p1; ++p) {
        int u = cs[p];
        int j = nodeIdx[u];
        if (j >= 0) row[j >> 5] |= (1u << (j & 31));
        int p3 = cp[u+1];
        for (int p2 = cp[u]; p2 < p3; ++p2) {
          int w2 = cs[p2];
          int j2 = nodeIdx[w2];
          if (j2 >= 0) row[j2 >> 5] |= (1u << (j2 & 31));
        }
      }
    }
    grid.sync();
    int rounds = 0;
    for (;;) {
      const int p = rounds & 1;
      unsigned* sw = selW + p*128;
      if (gid == 0) cn[12+p] = 0;
      for (int i = gid; i < A; i += NTHT) {
        if ((aliveW[i>>5] >> (i&31)) & 1u) {
          const unsigned* row = bs + (size_t)i*AW;
          int wlim = i >> 5;
          unsigned any = 0;
          for (int w2 = 0; w2 < wlim; ++w2) { any = row[w2] & aliveW[w2]; if (any) break; }
          if (!any) any = row[wlim] & aliveW[wlim] & ((i&31) ? ((1u<<(i&31))-1u) : 0u);
          if (!any) atomicOr(&sw[i>>5], 1u << (i&31));
        }
      }
      grid.sync();
      for (int ib = gid - lane; ib < A; ib += NTHT) {
        int i = ib + lane;
        bool aliveF = false;
        if (i < A && ((aliveW[i>>5] >> (i&31)) & 1u)) {
          const unsigned* row = bs + (size_t)i*AW;
          if ((sw[i>>5] >> (i&31)) & 1u) L.mis[S[i]] = 1;
          unsigned dead = 0;
          for (int w2 = 0; w2 < AW; ++w2) { dead = row[w2] & sw[w2]; if (dead) break; }
          if (dead) atomicAnd(&aliveW[i>>5], ~(1u << (i&31)));
          else aliveF = true;
        }
        unsigned long long mk = __ballot(aliveF);
        int cntw = __popcll(mk);
        if (cntw && lane == (__ffsll((unsigned long long)mk)-1)) atomicAdd(&cn[12+p], cntw);
      }
      if (gid < 128) selW[(1-p)*128 + gid] = 0;
      grid.sync();
      int ac = __hip_atomic_load(&cn[12+p], __ATOMIC_RELAXED, __HIP_MEMORY_SCOPE_AGENT);
      if (ac == 0 || rounds >= 100000) break;
      ++rounds;
    }
  }
}

// ---- final khop_min over (mis ? rank : n) ----
__global__ __launch_bounds__(BLOCK) void k_fin0(KParams P) {
  Lay L = mklay(P.ws, P.n, P.e);
  int v = blockIdx.x*BLOCK + threadIdx.x;
  if (v >= P.n) return;
  L.mm[v] = L.mis[v] ? L.rank[v] : P.n;
}
__global__ __launch_bounds__(BLOCK) void k_fin1(KParams P) {
  Lay L = mklay(P.ws, P.n, P.e);
  int v = blockIdx.x*BLOCK + threadIdx.x;
  if (v >= P.n) return;
  L.t1[v] = gmin_(L.colSrc, L.mm, L.colPtr[v], L.colPtr[v+1], L.mm[v]);
}
__global__ __launch_bounds__(BLOCK) void k_fin2(KParams P) {
  Lay L = mklay(P.ws, P.n, P.e);
  int v = blockIdx.x*BLOCK + threadIdx.x;
  if (v >= P.n) return;
  L.mr[v] = gmin_(L.colSrc, L.t1, L.colPtr[v], L.colPtr[v+1], L.t1[v]);
}

// ---- mis prefix scan -> misPre, num_mis, r2c ----
__global__ __launch_bounds__(BLOCK) void k_scanM1(KParams P) {
  Lay L = mklay(P.ws, P.n, P.e);
  __shared__ int lds[256];
  int tid = threadIdx.x, bid = blockIdx.x;
  int chunk = (P.n + SG - 1)/SG;
  int ig = bid*chunk + tid;
  bool valid = (tid < chunk) && (ig < P.n);
  int v2 = valid ? L.mis[ig] : 0;
  lds[tid] = v2; __syncthreads();
  for (int off = 1; off < 256; off <<= 1) {
    int t = (tid >= off) ? lds[tid-off] : 0; __syncthreads();
    lds[tid] += t; __syncthreads();
  }
  if (valid) L.misPre[ig] = lds[tid] - v2;
  if (tid == 0) L.btot[bid] = (unsigned)lds[255];
}
__global__ __launch_bounds__(BLOCK) void k_scanM3(KParams P) {
  Lay L = mklay(P.ws, P.n, P.e);
  int tid = threadIdx.x, bid = blockIdx.x;
  int chunk = (P.n + SG - 1)/SG;
  int ig = bid*chunk + tid;
  if (tid < chunk && ig < P.n) {
    int p = L.misPre[ig] + (int)L.bbase[bid];
    L.misPre[ig] = p;
    if (L.mis[ig]) L.r2c[L.rank[ig]] = p;
  }
}

__global__ __launch_bounds__(BLOCK) void k_clus(KParams P) {
  Lay L = mklay(P.ws, P.n, P.e);
  int gid = blockIdx.x*BLOCK + threadIdx.x;
  int M = L.cnts[2];
  long long M2 = (long long)M*M;
  for (int v = gid; v < P.n; v += NTHE) {
    int r3 = L.mr[v];
    L.clus[v] = (r3 >= 0 && r3 < P.n) ? L.r2c[r3] : 0;
  }
  bool pairOk = (M > 0) && (M2 < 0x7fffffffll) && (L.unionBase + M2 <= P.ws_ints);
  if (pairOk) {
    int m2i = (int)M2;
    for (int i = gid; i < m2i; i += NTHE) L.pairCnt[i] = 0;
  }
}

__global__ __launch_bounds__(BLOCK) void k_pair(KParams P) {
  Lay L = mklay(P.ws, P.n, P.e);
  int M = L.cnts[2];
  long long M2 = (long long)M*M;
  bool pairOk = (M > 0) && (M2 < 0x7fffffffll) && (L.unionBase + M2 <= P.ws_ints);
  if (!pairOk) return;
  const int* row = P.ei; const int* col = P.ei + P.e;
  int gid = blockIdx.x*BLOCK + threadIdx.x;
  for (int j = gid; j < P.e; j += NTHE) {
    int a = L.clus[row[j]], b2 = L.clus[col[j]];
    atomicAdd(&L.pairCnt[a*M + b2], 1);
  }
}

__global__ __launch_bounds__(BLOCK) void k_keep1(KParams P) {
  Lay L = mklay(P.ws, P.n, P.e);
  __shared__ int lds[256];
  int tid = threadIdx.x, bid = blockIdx.x;
  int M = L.cnts[2];
  long long M2 = (long long)M*M;
  bool pairOk = (M > 0) && (M2 < 0x7fffffffll) && (L.unionBase + M2 <= P.ws_ints);
  int m2i = pairOk ? (int)M2 : 0;
  int chunkP = pairOk ? (m2i + SG - 1)/SG : 0;
  int pstart = bid*chunkP; if (pstart > m2i) pstart = m2i;
  int pend = pstart + chunkP; if (pend > m2i) pend = m2i;
  int localKeep = 0;
  for (int i = pstart + tid; i < pend; i += BLOCK) {
    int c = L.pairCnt[i];
    if (c > 0 && (i / M) != (i % M)) ++localKeep;
  }
  lds[tid] = localKeep; __syncthreads();
  for (int off = 128; off > 0; off >>= 1) { if (tid < off) lds[tid] += lds[tid+off]; __syncthreads(); }
  if (tid == 0) L.btot[bid] = (unsigned)lds[0];
}

__global__ __launch_bounds__(BLOCK) void k_edges(KParams P) {
  Lay L = mklay(P.ws, P.n, P.e);
  __shared__ int lds[256];
  int tid = threadIdx.x, bid = blockIdx.x;
  int M = L.cnts[2], EK = L.cnts[3];
  long long M2 = (long long)M*M;
  bool pairOk = (M > 0) && (M2 < 0x7fffffffll) && (L.unionBase + M2 <= P.ws_ints);
  if (!pairOk) return;
  int m2i = (int)M2;
  int chunkP = (m2i + SG - 1)/SG;
  int pstart = bid*chunkP; if (pstart > m2i) pstart = m2i;
  int pend = pstart + chunkP; if (pend > m2i) pend = m2i;
  size_t eBase = (size_t)M * (size_t)P.d;
  bool outOk = (eBase + 3ull*(size_t)EK <= (size_t)P.out_size);
  int running2 = (int)L.bbase[bid];
  for (int t0 = pstart; t0 < pend; t0 += BLOCK) {
    int i = t0 + tid;
    int c = 0, kept = 0, a = 0, b2 = 0;
    if (i < pend) {
      c = L.pairCnt[i];
      a = i / M; b2 = i % M;
      kept = (c > 0 && a != b2) ? 1 : 0;
    }
    lds[tid] = kept; __syncthreads();
    for (int off = 1; off < 256; off <<= 1) {
      int t = (tid >= off) ? lds[tid-off] : 0; __syncthreads();
      lds[tid] += t; __syncthreads();
    }
    int incl = lds[tid], tot = lds[255];
    if (kept && outOk) {
      int j2 = running2 + incl - 1;
      P.out[eBase + (size_t)j2] = (float)a;
      P.out[eBase + (size_t)EK + (size_t)j2] = (float)b2;
      P.out[eBase + 2ull*(size_t)EK + (size_t)j2] = (float)c;
    }
    running2 += tot;
    __syncthreads();
  }
}

__global__ __launch_bounds__(BLOCK) void k_xpool(KParams P) {
  Lay L = mklay(P.ws, P.n, P.e);
  int gid = blockIdx.x*BLOCK + threadIdx.x;
  int lane = gid & 63, gwv = gid >> 6;
  int M = L.cnts[2];
  int d4 = P.d >> 2;
  size_t eBase = (size_t)M * (size_t)P.d;
  if (eBase > (size_t)P.out_size) return;
  for (int v = gwv; v < P.n; v += NWVE) {
    if (L.mis[v]) {
      int p = L.misPre[v];
      float sc = L.score[v];
      const float4* xr = (const float4*)(P.x + (size_t)v*P.d);
      float4* outr = (float4*)P.out + (size_t)p*d4;
      for (int q = lane; q < d4; q += 64) {
        float4 xv = xr[q];
        outr[q] = make_float4(xv.x*sc, xv.y*sc, xv.z*sc, xv.w*sc);
      }
    }
  }
}

extern "C" void kernel_launch(void* const* d_in, const int* in_sizes, int n_in,
                              void* d_out, int out_size, void* d_ws, size_t ws_size,
                              hipStream_t stream) {
  KParams P;
  P.x  = (const float*)d_in[0];
  P.ei = (const int*)d_in[1];
  P.w  = (const float*)d_in[2];
  P.bb = (const float*)d_in[3];
  P.out = (float*)d_out;
  P.d = in_sizes[2];            // 256
  P.n = in_sizes[0] / P.d;      // 100000
  P.e = in_sizes[1] / 2;        // 1600000
  P.out_size = out_size;
  P.ws = (int*)d_ws;
  P.ws_ints = (long long)(ws_size / 4);
  const int nblk = (P.n + BLOCK - 1) / BLOCK;

  k_score <<<EGRID, BLOCK, 0, stream>>>(P);
  k_degree<<<EGRID, BLOCK, 0, stream>>>(P);
  k_scan1 <<<SG,    BLOCK, 0, stream>>>(P);
  k_scanB <<<1, 64, 0, stream>>>(P, SG, -1);
  k_scan3 <<<SG,    BLOCK, 0, stream>>>(P);
  k_csr   <<<EGRID, BLOCK, 0, stream>>>(P);
  k_keygen<<<nblk,  BLOCK, 0, stream>>>(P);
  for (int pass = 0; pass < 4; ++pass) {
    k_sort_local  <<<SG, BLOCK, 0, stream>>>(P, pass);
    k_sort_scan1  <<<64, BLOCK, 0, stream>>>(P);
    k_scanD       <<<1, 64,    0, stream>>>(P);
    k_sort_scatter<<<SG, BLOCK, 0, stream>>>(P, pass);
  }
  k_rankinit<<<nblk, BLOCK, 0, stream>>>(P);
  for (int t = 0; t < DENSE_ITERS; ++t) {
    int first = (t == 0) ? 1 : 0;
    k_dmin <<<nblk, BLOCK, 0, stream>>>(P);
    k_dsel <<<nblk, BLOCK, 0, stream>>>(P, first);
    k_dor  <<<nblk, BLOCK, 0, stream>>>(P);
    k_drb  <<<nblk, BLOCK, 0, stream>>>(P, first);
    k_dflip<<<1, 1, 0, stream>>>(P);
  }
  void* args[] = { &P };
  hipLaunchCooperativeKernel((const void*)k_tail, dim3(TGRID), dim3(BLOCK), args, 0, stream);
  k_fin0<<<nblk, BLOCK, 0, stream>>>(P);
  k_fin1<<<nblk, BLOCK, 0, stream>>>(P);
  k_fin2<<<nblk, BLOCK, 0, stream>>>(P);
  k_scanM1<<<SG, BLOCK, 0, stream>>>(P);
  k_scanB <<<1, 64, 0, stream>>>(P, SG, 2);
  k_scanM3<<<SG, BLOCK, 0, stream>>>(P);
  k_clus <<<EGRID, BLOCK, 0, stream>>>(P);
  k_pair <<<EGRID, BLOCK, 0, stream>>>(P);
  k_keep1<<<SG,    BLOCK, 0, stream>>>(P);
  k_scanB<<<1, 64, 0, stream>>>(P, SG, 3);
  k_edges<<<SG,    BLOCK, 0, stream>>>(P);
  k_xpool<<<EGRID, BLOCK, 0, stream>>>(P);
}

// Round 7
// 1351.215 us; speedup vs baseline: 1.6676x; 1.0230x over previous
//
#include <hip/hip_runtime.h>
#include <math.h>

#define BLOCK 256
#define EGRID 2048                 // edge-parallel / bulk kernels
#define SG    512                  // scan/sort kernels (fixed structure)
#define NTHE (EGRID*BLOCK)
#define NWVE (NTHE/64)
#define INF_ 0x7fffffff
#define TB   6000                  // bitset-tail threshold (capacity ~7155)
#define AWMAX 224
#define DENSE_ITERS 6

struct KParams {
  const float* x;
  const int*   ei;
  const float* w;
  const float* bb;
  float* out;
  int n, e, d, out_size;
  int* ws;
  long long ws_ints;
};

struct Lay {
  float* score; int *ks1,*cursor;
  int *keyA,*idxA,*keyB,*idxB,*lrank;
  int *rank,*mr,*t1,*mis,*mm,*misPre,*r2c,*clus,*colPtr,*rowPtr;
  unsigned *bh,*dtot,*dbase,*btot,*bbase;
  int *cnts,*colSrc,*rowDst,*pairCnt;
  long long unionBase;
};

__device__ __host__ inline Lay mklay(int* ws, int n, int e) {
  Lay L;
  L.score=(float*)ws;
  L.ks1   = ws + (size_t)1*n;
  L.cursor= ws + (size_t)2*n;          // CSR cursor -> nodeIdx (tail)
  L.keyA  = ws + (size_t)3*n;          // sort key -> active list parity 0
  L.idxA  = ws + (size_t)4*n;          // sort payload: idxA[i]=node with rank i
  L.keyB  = ws + (size_t)5*n;          // sort key -> active list parity 1
  L.idxB  = ws + (size_t)6*n;
  L.lrank = ws + (size_t)7*n;          // sort tmp -> tail sorted list S
  L.rank  = ws + (size_t)8*n;
  L.mr    = ws + (size_t)9*n;          // tmin temp; final khop result
  L.t1    = ws + (size_t)10*n;         // tor temp; tcomp prefix; fin temp
  L.mis   = ws + (size_t)11*n;
  L.mm    = ws + (size_t)12*n;         // a[] = active?rank:INF; then fin0 output
  L.misPre= ws + (size_t)13*n;         // post misPre
  L.r2c   = ws + (size_t)14*n;
  L.clus  = ws + (size_t)15*n;
  L.colPtr= ws + (size_t)16*n;         // n+1
  L.rowPtr= ws + (size_t)17*n + 64;    // unused (layout keep)
  int* sm = ws + (size_t)18*n + 128;
  L.bh    = (unsigned*)sm;             // 256*SG
  L.dtot  = L.bh + 256*SG;             // 256
  L.dbase = L.dtot + 256;              // 256 (unused now)
  L.btot  = L.dbase + 256;             // SG
  L.bbase = L.btot + SG;               // SG (unused now)
  L.cnts  = (int*)(L.bbase + SG);      // 16
  L.unionBase = 18ll*n + 128 + 256ll*SG + 512 + 2ll*SG + 16;
  L.colSrc  = ws + L.unionBase;        // e ints (in-CSR)
  L.rowDst  = L.colSrc + e;            // e ints -> tail bitset rows (bs)
  L.pairCnt = ws + L.unionBase;        // M*M ints (aliased, post-loop)
  return L;
}

// ---- unrolled gather reducers ----
__device__ inline int gmin_(const int* __restrict__ s, const int* __restrict__ val,
                            int p, int pe, int m) {
  for (; p+3 < pe; p += 4) {
    int a0=s[p],a1=s[p+1],a2=s[p+2],a3=s[p+3];
    int t0=val[a0],t1=val[a1],t2=val[a2],t3=val[a3];
    t0=min(t0,t1); t2=min(t2,t3); t0=min(t0,t2); if (t0<m) m=t0;
  }
  for (; p<pe; ++p){ int t=val[s[p]]; if (t<m) m=t; }
  return m;
}
__device__ inline int gor_(const int* __restrict__ s, const int* __restrict__ val,
                           int p, int pe, int m) {
  for (; p+3 < pe; p += 4) m |= val[s[p]] | val[s[p+1]] | val[s[p+2]] | val[s[p+3]];
  for (; p<pe; ++p) m |= val[s[p]];
  return m;
}
__device__ inline int gsum_(const int* __restrict__ s, const int* __restrict__ val,
                            int p, int pe, int m) {
  for (; p+3 < pe; p += 4) m += val[s[p]] + val[s[p+1]] + val[s[p+2]] + val[s[p+3]];
  for (; p<pe; ++p) m += val[s[p]];
  return m;
}

// sum of btot[0..upto) within a 256-thread block (barrier-protected shared reuse)
__device__ inline int btotPrefix(const unsigned* btot, int upto) {
  __shared__ int red[256];
  int tid = threadIdx.x;
  int partial = 0;
  for (int idx = tid; idx < upto; idx += 256) partial += (int)btot[idx];
  __syncthreads();
  red[tid] = partial; __syncthreads();
  for (int off = 128; off > 0; off >>= 1) { if (tid < off) red[tid] += red[tid+off]; __syncthreads(); }
  int r = red[0]; __syncthreads();
  return r;
}

// ---------------- phase kernels ----------------
__global__ __launch_bounds__(BLOCK) void k_score(KParams P) {
  Lay L = mklay(P.ws, P.n, P.e);
  int gid = blockIdx.x*BLOCK + threadIdx.x;
  int lane = gid & 63, gwv = gid >> 6;
  int d4 = P.d >> 2;
  double bconst = (double)P.bb[0];
  const float4* w4 = (const float4*)P.w;
  for (int v = gwv; v < P.n; v += NWVE) {
    const float4* xr = (const float4*)(P.x + (size_t)v*P.d);
    double s = 0.0;
    for (int q = lane; q < d4; q += 64) {
      float4 xv = xr[q], wv = w4[q];
      s += (double)xv.x*wv.x + (double)xv.y*wv.y + (double)xv.z*wv.z + (double)xv.w*wv.w;
    }
    for (int off = 32; off > 0; off >>= 1) s += __shfl_down(s, off);
    if (lane == 0) L.score[v] = (float)(1.0/(1.0+exp(-(s+bconst))));
  }
  for (int v = gid; v < P.n; v += NTHE) L.ks1[v] = 0;
}

__global__ __launch_bounds__(BLOCK) void k_degree(KParams P) {
  Lay L = mklay(P.ws, P.n, P.e);
  const int* col = P.ei + P.e;
  int gid = blockIdx.x*BLOCK + threadIdx.x;
  for (int j = gid; j < P.e; j += NTHE) atomicAdd(&L.ks1[col[j]], 1);
}

__global__ __launch_bounds__(BLOCK) void k_scan1(KParams P) {
  Lay L = mklay(P.ws, P.n, P.e);
  __shared__ int lds[256];
  int tid = threadIdx.x, bid = blockIdx.x;
  int chunk = (P.n + SG - 1)/SG;
  int ig = bid*chunk + tid;
  bool valid = (tid < chunk) && (ig < P.n);
  int v2 = valid ? L.ks1[ig] : 0;
  lds[tid] = v2; __syncthreads();
  for (int off = 1; off < 256; off <<= 1) {
    int t = (tid >= off) ? lds[tid-off] : 0; __syncthreads();
    lds[tid] += t; __syncthreads();
  }
  if (valid) L.colPtr[ig] = lds[tid] - v2;
  if (tid == 0) L.btot[bid] = (unsigned)lds[255];
}

// colPtr += prefix(btot); cursor=colPtr; ks1+=1  (btot scan folded in)
__global__ __launch_bounds__(BLOCK) void k_scan3(KParams P) {
  Lay L = mklay(P.ws, P.n, P.e);
  int tid = threadIdx.x, bid = blockIdx.x;
  int base = btotPrefix(L.btot, bid);
  int chunk = (P.n + SG - 1)/SG;
  int ig = bid*chunk + tid;
  if (tid < chunk && ig < P.n) {
    int cp = L.colPtr[ig] + base;
    L.colPtr[ig] = cp; L.cursor[ig] = cp; L.ks1[ig] += 1;
  }
  if (bid == 0 && tid == 0) L.colPtr[P.n] = P.e;
}

__global__ __launch_bounds__(BLOCK) void k_csr(KParams P) {
  Lay L = mklay(P.ws, P.n, P.e);
  const int* row = P.ei; const int* col = P.ei + P.e;
  int gid = blockIdx.x*BLOCK + threadIdx.x;
  for (int j = gid; j < P.e; j += NTHE) {
    int pos = atomicAdd(&L.cursor[col[j]], 1);
    L.colSrc[pos] = row[j];
  }
}

__global__ __launch_bounds__(BLOCK) void k_keygen(KParams P) {
  Lay L = mklay(P.ws, P.n, P.e);
  int v = blockIdx.x*BLOCK + threadIdx.x;
  if (v >= P.n) return;
  int s = gsum_(L.colSrc, L.ks1, L.colPtr[v], L.colPtr[v+1], L.ks1[v]);
  float upd = L.score[v] / (float)s;
  unsigned u = __float_as_uint(upd);
  u = (u & 0x80000000u) ? (~u) : (u | 0x80000000u);
  ((unsigned*)L.keyA)[v] = ~u;
  ((unsigned*)L.idxA)[v] = (unsigned)v;
}

__global__ __launch_bounds__(BLOCK) void k_sort_local(KParams P, int pass) {
  Lay L = mklay(P.ws, P.n, P.e);
  __shared__ int ldsH[1024];
  int tid = threadIdx.x, bid = blockIdx.x, lane = tid & 63, wib = tid >> 6;
  unsigned* sk = (pass & 1) ? (unsigned*)L.keyB : (unsigned*)L.keyA;
  int shift = pass*8;
  for (int i = tid; i < 1024; i += BLOCK) ldsH[i] = 0;
  __syncthreads();
  int chunk = (P.n + SG - 1)/SG;
  int ig = bid*chunk + tid;
  bool valid = (tid < chunk) && (ig < P.n);
  int dig = 0;
  if (valid) dig = (int)((sk[ig] >> shift) & 255u);
  unsigned long long mmask = __ballot(valid);
  for (int b = 0; b < 8; ++b) {
    unsigned long long bm = __ballot((dig >> b) & 1);
    mmask &= ((dig >> b) & 1) ? bm : ~bm;
  }
  int lp = 0;
  if (valid) {
    lp = __popcll(mmask & ((1ull << lane) - 1ull));
    if (lp == 0) ldsH[wib*256 + dig] = __popcll(mmask);
  }
  __syncthreads();
  if (tid < 256) {
    int c0=ldsH[tid], c1=ldsH[256+tid], c2=ldsH[512+tid], c3=ldsH[768+tid];
    ldsH[tid]=0; ldsH[256+tid]=c0; ldsH[512+tid]=c0+c1; ldsH[768+tid]=c0+c1+c2;
    L.bh[(size_t)tid*SG + bid] = (unsigned)(c0+c1+c2+c3);
  }
  __syncthreads();
  if (valid) ((unsigned*)L.lrank)[ig] = (unsigned)(ldsH[wib*256 + dig] + lp);
}

__global__ __launch_bounds__(BLOCK) void k_sort_scan1(KParams P) {
  Lay L = mklay(P.ws, P.n, P.e);
  int g = blockIdx.x*BLOCK + threadIdx.x;
  int dg = g >> 6, lane = g & 63;
  if (dg >= 256) return;
  unsigned running = 0;
  for (int r = 0; r < SG/64; ++r) {
    unsigned v = L.bh[(size_t)dg*SG + r*64 + lane];
    unsigned incl = v;
    for (int off = 1; off < 64; off <<= 1) { unsigned t = __shfl_up(incl, off); if (lane >= off) incl += t; }
    L.bh[(size_t)dg*SG + r*64 + lane] = incl - v + running;
    running += __shfl(incl, 63);
  }
  if (lane == 0) L.dtot[dg] = running;
}

// scatter with in-block dbase recompute (scanD folded in)
__global__ __launch_bounds__(BLOCK) void k_sort_scatter(KParams P, int pass) {
  Lay L = mklay(P.ws, P.n, P.e);
  __shared__ unsigned sdb[256];
  unsigned *sk,*si,*dk,*di;
  if (pass & 1) { sk=(unsigned*)L.keyB; si=(unsigned*)L.idxB; dk=(unsigned*)L.keyA; di=(unsigned*)L.idxA; }
  else          { sk=(unsigned*)L.keyA; si=(unsigned*)L.idxA; dk=(unsigned*)L.keyB; di=(unsigned*)L.idxB; }
  int tid = threadIdx.x, bid = blockIdx.x;
  unsigned myv = L.dtot[tid];
  sdb[tid] = myv; __syncthreads();
  for (int off = 1; off < 256; off <<= 1) {
    unsigned t = (tid >= off) ? sdb[tid-off] : 0u; __syncthreads();
    sdb[tid] += t; __syncthreads();
  }
  unsigned excl = sdb[tid] - myv; __syncthreads();
  sdb[tid] = excl; __syncthreads();
  int chunk = (P.n + SG - 1)/SG;
  int ig = bid*chunk + tid;
  if (tid < chunk && ig < P.n) {
    unsigned key = sk[ig];
    int dig = (int)((key >> (pass*8)) & 255u);
    unsigned pos = sdb[dig] + L.bh[(size_t)dig*SG + bid] + ((unsigned*)L.lrank)[ig];
    dk[pos] = key; di[pos] = si[ig];
  }
}

__global__ __launch_bounds__(BLOCK) void k_rankinit(KParams P) {
  Lay L = mklay(P.ws, P.n, P.e);
  int i = blockIdx.x*BLOCK + threadIdx.x;
  if (blockIdx.x == 0 && threadIdx.x == 0) {
    L.cnts[4] = P.n;   // A for parity 0
    L.cnts[5] = 0;
  }
  if (i >= P.n) return;
  int v = (int)((unsigned*)L.idxA)[i];
  L.rank[v] = i;
  L.mm[v] = i;        // a[] = rank (all active)
  L.mis[v] = 0;
}

// ---- dense KMIS iterations (static parity = t&1) ----
__global__ __launch_bounds__(BLOCK) void k_dmin(KParams P, int t) {
  Lay L = mklay(P.ws, P.n, P.e);
  if (L.cnts[4+(t&1)] <= TB) return;
  int w = blockIdx.x*BLOCK + threadIdx.x;
  if (w >= P.n) return;
  L.mr[w] = gmin_(L.colSrc, L.mm, L.colPtr[w], L.colPtr[w+1], L.mm[w]);
}
__global__ __launch_bounds__(BLOCK) void k_dsel(KParams P, int t) {
  Lay L = mklay(P.ws, P.n, P.e);
  int q = t & 1;
  int A = L.cnts[4+q];
  if (A <= TB) return;
  int i = blockIdx.x*BLOCK + threadIdx.x;
  if (i >= A) return;
  int v = (t == 0) ? i : (q ? L.keyB : L.keyA)[i];
  int m2 = gmin_(L.colSrc, L.mr, L.colPtr[v], L.colPtr[v+1], L.mr[v]);
  if (L.rank[v] == m2) L.mis[v] = 1;
}
__global__ __launch_bounds__(BLOCK) void k_dor(KParams P, int t) {
  Lay L = mklay(P.ws, P.n, P.e);
  int q = t & 1;
  if (L.cnts[4+q] <= TB) return;
  int w = blockIdx.x*BLOCK + threadIdx.x;
  if (blockIdx.x == 0 && threadIdx.x == 0) L.cnts[4+(1-q)] = 0;
  if (w >= P.n) return;
  L.t1[w] = gor_(L.colSrc, L.mis, L.colPtr[w], L.colPtr[w+1], L.mis[w]);
}
__global__ __launch_bounds__(BLOCK) void k_drb(KParams P, int t) {
  Lay L = mklay(P.ws, P.n, P.e);
  int q = t & 1;
  int A = L.cnts[4+q];
  int* act  = (t == 0) ? (int*)0 : (q ? L.keyB : L.keyA);
  int* nact = q ? L.keyA : L.keyB;
  int gid = blockIdx.x*BLOCK + threadIdx.x;
  if (A <= TB) {                       // copy mode: keep parity flipping static
    for (int i = gid; i < A; i += (P.n + BLOCK - 1)/BLOCK*BLOCK) nact[i] = act[i];
    if (gid == 0) L.cnts[4+(1-q)] = A;
    return;
  }
  int lane = threadIdx.x & 63;
  bool aliveF = false; int v = 0;
  if (gid < A) {
    v = (t == 0) ? gid : act[gid];
    int dead = gor_(L.colSrc, L.t1, L.colPtr[v], L.colPtr[v+1], L.t1[v]);
    if (dead) L.mm[v] = INF_; else aliveF = true;
  }
  unsigned long long mk = __ballot(aliveF);
  int cntw = __popcll(mk);
  if (cntw) {
    int fl = __ffsll((unsigned long long)mk) - 1;
    int base = 0;
    if (lane == fl) base = atomicAdd(&L.cnts[4+(1-q)], cntw);
    base = __shfl(base, fl);
    if (aliveF) nact[base + __popcll(mk & ((1ull<<lane)-1ull))] = v;
  }
}

// ---- tail: compact survivors in rank order (flags via mm != INF over idxA) ----
__global__ __launch_bounds__(BLOCK) void k_tcomp1(KParams P) {
  Lay L = mklay(P.ws, P.n, P.e);
  __shared__ int lds[256];
  int tid = threadIdx.x, bid = blockIdx.x;
  int chunk = (P.n + SG - 1)/SG;
  int ig = bid*chunk + tid;
  bool valid = (tid < chunk) && (ig < P.n);
  int f = 0;
  if (valid) { int v = (int)((unsigned*)L.idxA)[ig]; f = (L.mm[v] != INF_) ? 1 : 0; }
  lds[tid] = f; __syncthreads();
  for (int off = 1; off < 256; off <<= 1) {
    int t = (tid >= off) ? lds[tid-off] : 0; __syncthreads();
    lds[tid] += t; __syncthreads();
  }
  if (valid) L.t1[ig] = lds[tid] - f;
  if (tid == 0) L.btot[bid] = (unsigned)lds[255];
}
// S[pos]=v ordered by rank; cursor[v]=pos or -1; zero bs
__global__ __launch_bounds__(BLOCK) void k_tcomp3(KParams P) {
  Lay L = mklay(P.ws, P.n, P.e);
  int tid = threadIdx.x, bid = blockIdx.x;
  int base = btotPrefix(L.btot, bid);
  int chunk = (P.n + SG - 1)/SG;
  int ig = bid*chunk + tid;
  if (tid < chunk && ig < P.n) {
    int v = (int)((unsigned*)L.idxA)[ig];
    if (L.mm[v] != INF_) {
      int pos = L.t1[ig] + base;
      L.lrank[pos] = v;          // S
      L.cursor[v] = pos;         // nodeIdx
    } else L.cursor[v] = -1;
  }
  int A = L.cnts[4];
  if (A > 0) {
    int AW = (A + 31) >> 5;
    unsigned* bs = (unsigned*)L.rowDst;
    long long tot = (long long)A * AW;
    for (long long idx = (long long)bid*BLOCK + tid; idx < tot; idx += (long long)SG*BLOCK) bs[idx] = 0u;
  }
}
// build in2closed source bitsets, wave per row
__global__ __launch_bounds__(BLOCK) void k_tbuild(KParams P) {
  Lay L = mklay(P.ws, P.n, P.e);
  int A = L.cnts[4];
  if (A <= 0) return;
  int AW = (A + 31) >> 5;
  unsigned* bs = (unsigned*)L.rowDst;
  const int* __restrict__ cp = L.colPtr;
  const int* __restrict__ cs = L.colSrc;
  const int* __restrict__ nodeIdx = L.cursor;
  int gid = blockIdx.x*BLOCK + threadIdx.x;
  int lane = gid & 63, gwv = gid >> 6;
  int nW = (gridDim.x*BLOCK) >> 6;
  for (int i = gwv; i < A; i += nW) {
    int v = L.lrank[i];
    unsigned* row = bs + (size_t)i*AW;
    if (lane == 0) atomicOr(&row[i >> 5], 1u << (i & 31));
    int p0 = cp[v], p1 = cp[v+1];
    for (int p = p0 + lane; p < p1; p += 64) {
      int u = cs[p];
      int j = nodeIdx[u];
      if (j >= 0) atomicOr(&row[j >> 5], 1u << (j & 31));
      int p3 = cp[u+1];
      for (int p2 = cp[u]; p2 < p3; ++p2) {
        int w2 = cs[p2];
        int j2 = nodeIdx[w2];
        if (j2 >= 0) atomicOr(&row[j2 >> 5], 1u << (j2 & 31));
      }
    }
  }
}
// all MIS rounds in one 1024-thread block, aliveW/selW in LDS
__global__ __launch_bounds__(1024) void k_trounds(KParams P) {
  Lay L = mklay(P.ws, P.n, P.e);
  __shared__ unsigned aliveW[AWMAX];
  __shared__ unsigned selW[AWMAX];
  __shared__ int scnt;
  int A = L.cnts[4];
  if (A <= 0) return;
  int AW = (A + 31) >> 5;
  const unsigned* __restrict__ bs = (const unsigned*)L.rowDst;
  const int* __restrict__ S = L.lrank;
  int tid = threadIdx.x;
  for (int w = tid; w < AW; w += 1024) {
    int base = w*32; int c = A - base;
    aliveW[w] = (c >= 32) ? 0xffffffffu : ((c > 0) ? ((1u << c) - 1u) : 0u);
  }
  __syncthreads();
  for (int rounds = 0; rounds < 8192; ++rounds) {
    for (int w = tid; w < AW; w += 1024) selW[w] = 0u;
    if (tid == 0) scnt = 0;
    __syncthreads();
    // ph1: select alive i with no alive smaller-ranked in-2 source
    for (int i = tid; i < A; i += 1024) {
      if ((aliveW[i>>5] >> (i&31)) & 1u) {
        const unsigned* row = bs + (size_t)i*AW;
        int wl = i >> 5;
        unsigned any = 0;
        for (int w2 = 0; w2 < wl; ++w2) { any = row[w2] & aliveW[w2]; if (any) break; }
        if (!any && (i & 31)) any = row[wl] & aliveW[wl] & ((1u << (i&31)) - 1u);
        if (!any) { atomicOr(&selW[i>>5], 1u << (i&31)); L.mis[S[i]] = 1; }
      }
    }
    __syncthreads();
    // ph2: kill anything whose in-2 sources intersect selected (incl. self)
    int surv = 0;
    for (int i = tid; i < A; i += 1024) {
      if ((aliveW[i>>5] >> (i&31)) & 1u) {
        const unsigned* row = bs + (size_t)i*AW;
        unsigned dead = 0;
        for (int w2 = 0; w2 < AW; ++w2) { dead = row[w2] & selW[w2]; if (dead) break; }
        if (dead) atomicAnd(&aliveW[i>>5], ~(1u << (i&31)));
        else ++surv;
      }
    }
    if (surv) atomicAdd(&scnt, surv);
    __syncthreads();
    int sc = scnt;
    __syncthreads();
    if (sc == 0) break;
  }
}

// ---- final khop_min; fin0 folded into scanM1 ----
__global__ __launch_bounds__(BLOCK) void k_scanM1(KParams P) {
  Lay L = mklay(P.ws, P.n, P.e);
  __shared__ int lds[256];
  int tid = threadIdx.x, bid = blockIdx.x;
  int chunk = (P.n + SG - 1)/SG;
  int ig = bid*chunk + tid;
  bool valid = (tid < chunk) && (ig < P.n);
  int v2 = 0;
  if (valid) {
    v2 = L.mis[ig];
    L.mm[ig] = v2 ? L.rank[ig] : P.n;   // fin0
  }
  lds[tid] = v2; __syncthreads();
  for (int off = 1; off < 256; off <<= 1) {
    int t = (tid >= off) ? lds[tid-off] : 0; __syncthreads();
    lds[tid] += t; __syncthreads();
  }
  if (valid) L.misPre[ig] = lds[tid] - v2;
  if (tid == 0) L.btot[bid] = (unsigned)lds[255];
}
__global__ __launch_bounds__(BLOCK) void k_fin1(KParams P) {
  Lay L = mklay(P.ws, P.n, P.e);
  int v = blockIdx.x*BLOCK + threadIdx.x;
  if (v >= P.n) return;
  L.t1[v] = gmin_(L.colSrc, L.mm, L.colPtr[v], L.colPtr[v+1], L.mm[v]);
}
__global__ __launch_bounds__(BLOCK) void k_fin2(KParams P) {
  Lay L = mklay(P.ws, P.n, P.e);
  int v = blockIdx.x*BLOCK + threadIdx.x;
  if (v >= P.n) return;
  L.mr[v] = gmin_(L.colSrc, L.t1, L.colPtr[v], L.colPtr[v+1], L.t1[v]);
}
// misPre += prefix(btot); r2c; cnts[2]=num_mis  (scanB folded)
__global__ __launch_bounds__(BLOCK) void k_scanM3(KParams P) {
  Lay L = mklay(P.ws, P.n, P.e);
  int tid = threadIdx.x, bid = blockIdx.x;
  int base = btotPrefix(L.btot, bid);
  int total = btotPrefix(L.btot, SG);
  int chunk = (P.n + SG - 1)/SG;
  int ig = bid*chunk + tid;
  if (tid < chunk && ig < P.n) {
    int p = L.misPre[ig] + base;
    L.misPre[ig] = p;
    if (L.mis[ig]) L.r2c[L.rank[ig]] = p;
  }
  if (bid == 0 && tid == 0) L.cnts[2] = total;
}

__global__ __launch_bounds__(BLOCK) void k_clus(KParams P) {
  Lay L = mklay(P.ws, P.n, P.e);
  int gid = blockIdx.x*BLOCK + threadIdx.x;
  int M = L.cnts[2];
  long long M2 = (long long)M*M;
  for (int v = gid; v < P.n; v += NTHE) {
    int r3 = L.mr[v];
    L.clus[v] = (r3 >= 0 && r3 < P.n) ? L.r2c[r3] : 0;
  }
  bool pairOk = (M > 0) && (M2 < 0x7fffffffll) && (L.unionBase + M2 <= P.ws_ints);
  if (pairOk) {
    int m2i = (int)M2;
    for (int i = gid; i < m2i; i += NTHE) L.pairCnt[i] = 0;
  }
}

__global__ __launch_bounds__(BLOCK) void k_pair(KParams P) {
  Lay L = mklay(P.ws, P.n, P.e);
  int M = L.cnts[2];
  long long M2 = (long long)M*M;
  bool pairOk = (M > 0) && (M2 < 0x7fffffffll) && (L.unionBase + M2 <= P.ws_ints);
  if (!pairOk) return;
  const int* row = P.ei; const int* col = P.ei + P.e;
  int gid = blockIdx.x*BLOCK + threadIdx.x;
  for (int j = gid; j < P.e; j += NTHE) {
    int a = L.clus[row[j]], b2 = L.clus[col[j]];
    atomicAdd(&L.pairCnt[a*M + b2], 1);
  }
}

__global__ __launch_bounds__(BLOCK) void k_keep1(KParams P) {
  Lay L = mklay(P.ws, P.n, P.e);
  __shared__ int lds[256];
  int tid = threadIdx.x, bid = blockIdx.x;
  int M = L.cnts[2];
  long long M2 = (long long)M*M;
  bool pairOk = (M > 0) && (M2 < 0x7fffffffll) && (L.unionBase + M2 <= P.ws_ints);
  int m2i = pairOk ? (int)M2 : 0;
  int chunkP = pairOk ? (m2i + SG - 1)/SG : 0;
  int pstart = bid*chunkP; if (pstart > m2i) pstart = m2i;
  int pend = pstart + chunkP; if (pend > m2i) pend = m2i;
  int localKeep = 0;
  for (int i = pstart + tid; i < pend; i += BLOCK) {
    int c = L.pairCnt[i];
    if (c > 0 && (i / M) != (i % M)) ++localKeep;
  }
  lds[tid] = localKeep; __syncthreads();
  for (int off = 128; off > 0; off >>= 1) { if (tid < off) lds[tid] += lds[tid+off]; __syncthreads(); }
  if (tid == 0) L.btot[bid] = (unsigned)lds[0];
}

__global__ __launch_bounds__(BLOCK) void k_edges(KParams P) {
  Lay L = mklay(P.ws, P.n, P.e);
  __shared__ int lds[256];
  int tid = threadIdx.x, bid = blockIdx.x;
  int M = L.cnts[2];
  long long M2 = (long long)M*M;
  bool pairOk = (M > 0) && (M2 < 0x7fffffffll) && (L.unionBase + M2 <= P.ws_ints);
  if (!pairOk) return;
  int base = btotPrefix(L.btot, bid);
  int EK = btotPrefix(L.btot, SG);
  int m2i = (int)M2;
  int chunkP = (m2i + SG - 1)/SG;
  int pstart = bid*chunkP; if (pstart > m2i) pstart = m2i;
  int pend = pstart + chunkP; if (pend > m2i) pend = m2i;
  size_t eBase = (size_t)M * (size_t)P.d;
  bool outOk = (eBase + 3ull*(size_t)EK <= (size_t)P.out_size);
  int running2 = base;
  for (int t0 = pstart; t0 < pend; t0 += BLOCK) {
    int i = t0 + tid;
    int c = 0, kept = 0, a = 0, b2 = 0;
    if (i < pend) {
      c = L.pairCnt[i];
      a = i / M; b2 = i % M;
      kept = (c > 0 && a != b2) ? 1 : 0;
    }
    lds[tid] = kept; __syncthreads();
    for (int off = 1; off < 256; off <<= 1) {
      int t = (tid >= off) ? lds[tid-off] : 0; __syncthreads();
      lds[tid] += t; __syncthreads();
    }
    int incl = lds[tid], tot = lds[255];
    if (kept && outOk) {
      int j2 = running2 + incl - 1;
      P.out[eBase + (size_t)j2] = (float)a;
      P.out[eBase + (size_t)EK + (size_t)j2] = (float)b2;
      P.out[eBase + 2ull*(size_t)EK + (size_t)j2] = (float)c;
    }
    running2 += tot;
    __syncthreads();
  }
}

__global__ __launch_bounds__(BLOCK) void k_xpool(KParams P) {
  Lay L = mklay(P.ws, P.n, P.e);
  int gid = blockIdx.x*BLOCK + threadIdx.x;
  int lane = gid & 63, gwv = gid >> 6;
  int M = L.cnts[2];
  int d4 = P.d >> 2;
  size_t eBase = (size_t)M * (size_t)P.d;
  if (eBase > (size_t)P.out_size) return;
  for (int v = gwv; v < P.n; v += NWVE) {
    if (L.mis[v]) {
      int p = L.misPre[v];
      float sc = L.score[v];
      const float4* xr = (const float4*)(P.x + (size_t)v*P.d);
      float4* outr = (float4*)P.out + (size_t)p*d4;
      for (int q = lane; q < d4; q += 64) {
        float4 xv = xr[q];
        outr[q] = make_float4(xv.x*sc, xv.y*sc, xv.z*sc, xv.w*sc);
      }
    }
  }
}

extern "C" void kernel_launch(void* const* d_in, const int* in_sizes, int n_in,
                              void* d_out, int out_size, void* d_ws, size_t ws_size,
                              hipStream_t stream) {
  KParams P;
  P.x  = (const float*)d_in[0];
  P.ei = (const int*)d_in[1];
  P.w  = (const float*)d_in[2];
  P.bb = (const float*)d_in[3];
  P.out = (float*)d_out;
  P.d = in_sizes[2];            // 256
  P.n = in_sizes[0] / P.d;      // 100000
  P.e = in_sizes[1] / 2;        // 1600000
  P.out_size = out_size;
  P.ws = (int*)d_ws;
  P.ws_ints = (long long)(ws_size / 4);
  const int nblk = (P.n + BLOCK - 1) / BLOCK;

  k_score <<<EGRID, BLOCK, 0, stream>>>(P);
  k_degree<<<EGRID, BLOCK, 0, stream>>>(P);
  k_scan1 <<<SG,    BLOCK, 0, stream>>>(P);
  k_scan3 <<<SG,    BLOCK, 0, stream>>>(P);
  k_csr   <<<EGRID, BLOCK, 0, stream>>>(P);
  k_keygen<<<nblk,  BLOCK, 0, stream>>>(P);
  for (int pass = 0; pass < 4; ++pass) {
    k_sort_local  <<<SG, BLOCK, 0, stream>>>(P, pass);
    k_sort_scan1  <<<64, BLOCK, 0, stream>>>(P);
    k_sort_scatter<<<SG, BLOCK, 0, stream>>>(P, pass);
  }
  k_rankinit<<<nblk, BLOCK, 0, stream>>>(P);
  for (int t = 0; t < DENSE_ITERS; ++t) {
    k_dmin <<<nblk, BLOCK, 0, stream>>>(P, t);
    k_dsel <<<nblk, BLOCK, 0, stream>>>(P, t);
    k_dor  <<<nblk, BLOCK, 0, stream>>>(P, t);
    k_drb  <<<nblk, BLOCK, 0, stream>>>(P, t);
  }
  k_tcomp1 <<<SG,   BLOCK, 0, stream>>>(P);
  k_tcomp3 <<<SG,   BLOCK, 0, stream>>>(P);
  k_tbuild <<<nblk, BLOCK, 0, stream>>>(P);
  k_trounds<<<1,    1024,  0, stream>>>(P);
  k_scanM1<<<SG, BLOCK, 0, stream>>>(P);
  k_fin1  <<<nblk, BLOCK, 0, stream>>>(P);
  k_fin2  <<<nblk, BLOCK, 0, stream>>>(P);
  k_scanM3<<<SG, BLOCK, 0, stream>>>(P);
  k_clus <<<EGRID, BLOCK, 0, stream>>>(P);
  k_pair <<<EGRID, BLOCK, 0, stream>>>(P);
  k_keep1<<<SG,    BLOCK, 0, stream>>>(P);
  k_edges<<<SG,    BLOCK, 0, stream>>>(P);
  k_xpool<<<EGRID, BLOCK, 0, stream>>>(P);
}